// Round 1
// baseline (1547.624 us; speedup 1.0000x reference)
//
#include <hip/hip_runtime.h>
#include <math.h>

// Problem constants
#define T_   8
#define K_   64
#define D_   512
#define CIN_ 1536
#define B_   32
#define S_   64    // H*W = 8*8
#define NT_  256   // B*T

// Workspace layout (float offsets)
#define WT_OFF    0u          // [1536][512] transposed redu_w
#define WXT_OFF   786432u     // [512][64]  transposed w_x
#define XT_OFF    819200u     // [256][512][64]
#define WXPB_OFF  9207808u    // [256][64][64]
#define ATTV_OFF  10256384u   // [256][64][64]  (n = b*8+t)
#define H_OFF     11304960u   // [32][64][64]
#define HS_OFF    11436032u   // [8][32][64][64]
#define EMEAN_OFF 12484608u   // [32][512]
#define EMAX_OFF  12500992u   // [32][512]
#define WXTP_OFF  12517376u   // [32][64][64]
#define WXTC_OFF  12648448u   // [32][64][64]
#define Z_OFF     12779520u   // [32][64][64]
#define RH_OFF    12910592u   // [32][64][64]
#define ASUM_OFF  13041664u   // [32][8][64]

// ---------------------------------------------------------------------------
// prep: transpose redu_w -> Wt[c][d], w_x -> wxT[d][k], zero h
__global__ __launch_bounds__(256) void k_prep(const float* __restrict__ redu_w,
                                              const float* __restrict__ w_x,
                                              float* __restrict__ ws) {
    unsigned idx = blockIdx.x * 256u + threadIdx.x;
    if (idx < 786432u) {
        unsigned c = idx >> 9, d = idx & 511u;
        ws[WT_OFF + idx] = redu_w[d * 1536u + c];
    } else if (idx < 819200u) {
        unsigned i = idx - 786432u;
        unsigned dd = i >> 6, k = i & 63u;
        ws[WXT_OFF + i] = w_x[k * 512u + dd];
    } else if (idx < 950272u) {
        ws[H_OFF + (idx - 819200u)] = 0.f;
    }
}

// ---------------------------------------------------------------------------
// xt = redu_w @ x + redu_b ; per n: (512x1536)@(1536x64)
// grid (2, 256), block 256. tile 256d x 64s, 8x8 per thread.
__global__ __launch_bounds__(256) void k_gemm_xt(const float* __restrict__ x,
                                                 const float* __restrict__ redu_b,
                                                 float* __restrict__ ws) {
    __shared__ float Ws[16 * 256];
    __shared__ float Xs[16 * 64];
    const float* Wt = ws + WT_OFF;
    float* xt = ws + XT_OFF;
    const int n = blockIdx.y;
    const int d0 = blockIdx.x * 256;
    const int tid = threadIdx.x;
    const int sg = tid & 7, dg = tid >> 3;   // dg in [0,32)

    float acc[8][8];
#pragma unroll
    for (int i = 0; i < 8; ++i)
#pragma unroll
        for (int j = 0; j < 8; ++j) acc[i][j] = 0.f;

    for (int c0 = 0; c0 < 1536; c0 += 16) {
#pragma unroll
        for (int k2 = 0; k2 < 4; ++k2) {
            int f = tid + k2 * 256;
            int cc = f >> 6, dq = f & 63;
            *(float4*)&Ws[cc * 256 + dq * 4] =
                *(const float4*)&Wt[(c0 + cc) * 512 + d0 + dq * 4];
        }
        {
            int cc = tid >> 4, sq = tid & 15;
            *(float4*)&Xs[cc * 64 + sq * 4] =
                *(const float4*)&x[n * 98304 + (c0 + cc) * 64 + sq * 4];
        }
        __syncthreads();
#pragma unroll
        for (int cc = 0; cc < 16; ++cc) {
            float4 a0 = *(const float4*)&Ws[cc * 256 + dg * 8];
            float4 a1 = *(const float4*)&Ws[cc * 256 + dg * 8 + 4];
            float4 b0 = *(const float4*)&Xs[cc * 64 + sg * 8];
            float4 b1 = *(const float4*)&Xs[cc * 64 + sg * 8 + 4];
            float av[8] = {a0.x, a0.y, a0.z, a0.w, a1.x, a1.y, a1.z, a1.w};
            float bv[8] = {b0.x, b0.y, b0.z, b0.w, b1.x, b1.y, b1.z, b1.w};
#pragma unroll
            for (int i = 0; i < 8; ++i)
#pragma unroll
                for (int j = 0; j < 8; ++j)
                    acc[i][j] = fmaf(av[i], bv[j], acc[i][j]);
        }
        __syncthreads();
    }
#pragma unroll
    for (int i = 0; i < 8; ++i) {
        int d = d0 + dg * 8 + i;
        float bias = redu_b[d];
        float4 o0 = {acc[i][0] + bias, acc[i][1] + bias, acc[i][2] + bias, acc[i][3] + bias};
        float4 o1 = {acc[i][4] + bias, acc[i][5] + bias, acc[i][6] + bias, acc[i][7] + bias};
        *(float4*)&xt[(n * 512 + d) * 64 + sg * 8] = o0;
        *(float4*)&xt[(n * 512 + d) * 64 + sg * 8 + 4] = o1;
    }
}

// ---------------------------------------------------------------------------
// wxpb = w_x @ xt ; per n: (64x512)@(512x64). grid 256, block 256, 4x4/thread.
__global__ __launch_bounds__(256) void k_gemm_wxpb(float* __restrict__ ws) {
    __shared__ float Aw[16 * 64];
    __shared__ float Bx[16 * 64];
    const float* wxT = ws + WXT_OFF;
    const float* xt = ws + XT_OFF;
    float* wxpb = ws + WXPB_OFF;
    const int n = blockIdx.x;
    const int tid = threadIdx.x;
    const int sg = tid & 15, kg = tid >> 4;

    float acc[4][4];
#pragma unroll
    for (int i = 0; i < 4; ++i)
#pragma unroll
        for (int j = 0; j < 4; ++j) acc[i][j] = 0.f;

    for (int d0 = 0; d0 < 512; d0 += 16) {
        int cc = tid >> 4, q = tid & 15;
        *(float4*)&Aw[cc * 64 + q * 4] = *(const float4*)&wxT[(d0 + cc) * 64 + q * 4];
        *(float4*)&Bx[cc * 64 + q * 4] = *(const float4*)&xt[n * 32768 + (d0 + cc) * 64 + q * 4];
        __syncthreads();
#pragma unroll
        for (int c2 = 0; c2 < 16; ++c2) {
            float4 a = *(const float4*)&Aw[c2 * 64 + kg * 4];
            float4 b = *(const float4*)&Bx[c2 * 64 + sg * 4];
            float av[4] = {a.x, a.y, a.z, a.w};
            float bv[4] = {b.x, b.y, b.z, b.w};
#pragma unroll
            for (int i = 0; i < 4; ++i)
#pragma unroll
                for (int j = 0; j < 4; ++j)
                    acc[i][j] = fmaf(av[i], bv[j], acc[i][j]);
        }
        __syncthreads();
    }
#pragma unroll
    for (int i = 0; i < 4; ++i) {
        float4 o = {acc[i][0], acc[i][1], acc[i][2], acc[i][3]};
        *(float4*)&wxpb[(n * 64 + kg * 4 + i) * 64 + sg * 4] = o;
    }
}

// ---------------------------------------------------------------------------
// generic 3x3 conv, pad=1, 64->16 channels per block (grid.x=4), one image per
// blockIdx.y. block 128: thread = (k_local(16), y(8)), 8 x-outputs in regs.
__global__ __launch_bounds__(128) void k_conv3x3(const float* __restrict__ in,
                                                 const float* __restrict__ wt,
                                                 const float* __restrict__ bias,
                                                 float* __restrict__ out) {
    __shared__ float in_s[4096];
    __shared__ float w_s[16 * 576];
    const int img = blockIdx.y;
    const int k0 = blockIdx.x * 16;
    const int tid = threadIdx.x;
    const int kl = tid >> 3, y = tid & 7;
#pragma unroll
    for (int i = 0; i < 8; ++i) {
        int f = tid + i * 128;
        *(float4*)&in_s[f * 4] = *(const float4*)&in[img * 4096 + f * 4];
    }
#pragma unroll
    for (int i = 0; i < 18; ++i) {
        int f = tid + i * 128;
        *(float4*)&w_s[f * 4] = *(const float4*)&wt[k0 * 576 + f * 4];
    }
    __syncthreads();
    float o[8];
#pragma unroll
    for (int xx = 0; xx < 8; ++xx) o[xx] = 0.f;
    for (int kp = 0; kp < 64; ++kp) {
        const float* wp = &w_s[kl * 576 + kp * 9];
        float wv[9];
#pragma unroll
        for (int q = 0; q < 9; ++q) wv[q] = wp[q];
#pragma unroll
        for (int dy = 0; dy < 3; ++dy) {
            int yy = y + dy - 1;
            if (yy >= 0 && yy < 8) {
                float4 ra = *(const float4*)&in_s[kp * 64 + yy * 8];
                float4 rb = *(const float4*)&in_s[kp * 64 + yy * 8 + 4];
                float r[8] = {ra.x, ra.y, ra.z, ra.w, rb.x, rb.y, rb.z, rb.w};
                float wa = wv[dy * 3 + 0], wb = wv[dy * 3 + 1], wc = wv[dy * 3 + 2];
#pragma unroll
                for (int xx = 0; xx < 8; ++xx) {
                    float t = wb * r[xx];
                    if (xx > 0) t += wa * r[xx - 1];
                    if (xx < 7) t += wc * r[xx + 1];
                    o[xx] += t;
                }
            }
        }
    }
    float bv = bias ? bias[k0 + kl] : 0.f;
    float4 o0 = {o[0] + bv, o[1] + bv, o[2] + bv, o[3] + bv};
    float4 o1 = {o[4] + bv, o[5] + bv, o[6] + bv, o[7] + bv};
    *(float4*)&out[img * 4096 + (k0 + kl) * 64 + y * 8] = o0;
    *(float4*)&out[img * 4096 + (k0 + kl) * 64 + y * 8 + 4] = o1;
}

// ---------------------------------------------------------------------------
// per step: ah = conv(h, att_h_w)+att_b ; e = relu(attv+ah); emean/emax over hw
__global__ __launch_bounds__(128) void k_step_ah_e(const float* __restrict__ att_h_w,
                                                   const float* __restrict__ att_b,
                                                   float* __restrict__ ws) {
    __shared__ float in_s[4096];
    __shared__ float w_s[16 * 576];
    const int b = blockIdx.y;
    const int k0 = blockIdx.x * 16;
    const int tid = threadIdx.x;
    const int kl = tid >> 3, y = tid & 7;
#pragma unroll
    for (int i = 0; i < 8; ++i) {
        int f = tid + i * 128;
        *(float4*)&in_s[f * 4] = *(const float4*)&ws[H_OFF + b * 4096 + f * 4];
    }
#pragma unroll
    for (int i = 0; i < 18; ++i) {
        int f = tid + i * 128;
        *(float4*)&w_s[f * 4] = *(const float4*)&att_h_w[k0 * 576 + f * 4];
    }
    __syncthreads();
    float ah[8];
#pragma unroll
    for (int xx = 0; xx < 8; ++xx) ah[xx] = 0.f;
    for (int kp = 0; kp < 64; ++kp) {
        const float* wp = &w_s[kl * 576 + kp * 9];
        float wv[9];
#pragma unroll
        for (int q = 0; q < 9; ++q) wv[q] = wp[q];
#pragma unroll
        for (int dy = 0; dy < 3; ++dy) {
            int yy = y + dy - 1;
            if (yy >= 0 && yy < 8) {
                float4 ra = *(const float4*)&in_s[kp * 64 + yy * 8];
                float4 rb = *(const float4*)&in_s[kp * 64 + yy * 8 + 4];
                float r[8] = {ra.x, ra.y, ra.z, ra.w, rb.x, rb.y, rb.z, rb.w};
                float wa = wv[dy * 3 + 0], wb = wv[dy * 3 + 1], wc = wv[dy * 3 + 2];
#pragma unroll
                for (int xx = 0; xx < 8; ++xx) {
                    float t = wb * r[xx];
                    if (xx > 0) t += wa * r[xx - 1];
                    if (xx < 7) t += wc * r[xx + 1];
                    ah[xx] += t;
                }
            }
        }
    }
    const int k = k0 + kl;
    const float ab = att_b[k];
#pragma unroll
    for (int xx = 0; xx < 8; ++xx) ah[xx] += ab;

    const float* attv = ws + ATTV_OFF;
    float* emean = ws + EMEAN_OFF;
    float* emax = ws + EMAX_OFF;
    for (int tp = 0; tp < 8; ++tp) {
        const float* av = &attv[((b * 8 + tp) * 64 + k) * 64 + y * 8];
        float4 va = *(const float4*)&av[0];
        float4 vb = *(const float4*)&av[4];
        float e[8] = {va.x, va.y, va.z, va.w, vb.x, vb.y, vb.z, vb.w};
        float s = 0.f, m = 0.f;
#pragma unroll
        for (int xx = 0; xx < 8; ++xx) {
            float v = fmaxf(e[xx] + ah[xx], 0.f);
            s += v;
            m = fmaxf(m, v);
        }
        s += __shfl_down(s, 4, 8);
        s += __shfl_down(s, 2, 8);
        s += __shfl_down(s, 1, 8);
        m = fmaxf(m, __shfl_down(m, 4, 8));
        m = fmaxf(m, __shfl_down(m, 2, 8));
        m = fmaxf(m, __shfl_down(m, 1, 8));
        if (y == 0) {
            emean[b * 512 + tp * 64 + k] = s * (1.f / 64.f);
            emax[b * 512 + tp * 64 + k] = m;
        }
    }
}

// ---------------------------------------------------------------------------
// per step: channel-attention MLP, softmax over T, and wxt_pre = sum_t a*wxpb
__global__ __launch_bounds__(256) void k_step_fc(const float* __restrict__ fc1_w,
                                                 const float* __restrict__ fc2_w,
                                                 float* __restrict__ ws) {
    __shared__ float em[512];
    __shared__ float ex[512];
    __shared__ float h1[64];
    __shared__ float exs[512];
    __shared__ float als[512];
    const int b = blockIdx.x;
    const int tid = threadIdx.x;
    em[tid] = ws[EMEAN_OFF + b * 512 + tid];
    em[tid + 256] = ws[EMEAN_OFF + b * 512 + tid + 256];
    ex[tid] = ws[EMAX_OFF + b * 512 + tid];
    ex[tid + 256] = ws[EMAX_OFF + b * 512 + tid + 256];
    __syncthreads();
    {
        int i2 = tid >> 2, part = tid & 3;
        int i = i2 & 31;
        const float* src = (i2 < 32) ? em : ex;
        const float* wrow = fc1_w + i * 512 + part * 128;
        const float* s2 = src + part * 128;
        float p = 0.f;
        for (int c = 0; c < 128; ++c) p = fmaf(wrow[c], s2[c], p);
        p += __shfl_down(p, 2, 4);
        p += __shfl_down(p, 1, 4);
        if (part == 0) h1[i2] = fmaxf(p, 0.f);
    }
    __syncthreads();
#pragma unroll
    for (int jj = 0; jj < 2; ++jj) {
        int j = tid + jj * 256;
        const float* w2 = fc2_w + j * 32;
        float gm = 0.f, gx = 0.f;
#pragma unroll
        for (int i = 0; i < 32; ++i) {
            gm = fmaf(w2[i], h1[i], gm);
            gx = fmaf(w2[i], h1[32 + i], gx);
        }
        exs[j] = expf(tanhf(gm + gx));
    }
    __syncthreads();
#pragma unroll
    for (int jj = 0; jj < 2; ++jj) {
        int j = tid + jj * 256;
        int kk = j & 63;
        float den = 0.f;
#pragma unroll
        for (int tp = 0; tp < 8; ++tp) den += exs[tp * 64 + kk];
        den += (den == 0.f) ? 1.f : 0.f;
        als[j] = exs[j] / den;
    }
    __syncthreads();
    // wxt_pre
    const float* wxpb = ws + WXPB_OFF;
    float* wxtp = ws + WXTP_OFF;
    int k = tid >> 2, g4 = tid & 3;
    float4 a0 = {0, 0, 0, 0}, a1 = {0, 0, 0, 0}, a2 = {0, 0, 0, 0}, a3 = {0, 0, 0, 0};
    for (int tp = 0; tp < 8; ++tp) {
        float al = als[tp * 64 + k];
        const float* src = &wxpb[((b * 8 + tp) * 64 + k) * 64 + g4 * 16];
        float4 v0 = *(const float4*)&src[0];
        float4 v1 = *(const float4*)&src[4];
        float4 v2 = *(const float4*)&src[8];
        float4 v3 = *(const float4*)&src[12];
        a0.x = fmaf(al, v0.x, a0.x); a0.y = fmaf(al, v0.y, a0.y);
        a0.z = fmaf(al, v0.z, a0.z); a0.w = fmaf(al, v0.w, a0.w);
        a1.x = fmaf(al, v1.x, a1.x); a1.y = fmaf(al, v1.y, a1.y);
        a1.z = fmaf(al, v1.z, a1.z); a1.w = fmaf(al, v1.w, a1.w);
        a2.x = fmaf(al, v2.x, a2.x); a2.y = fmaf(al, v2.y, a2.y);
        a2.z = fmaf(al, v2.z, a2.z); a2.w = fmaf(al, v2.w, a2.w);
        a3.x = fmaf(al, v3.x, a3.x); a3.y = fmaf(al, v3.y, a3.y);
        a3.z = fmaf(al, v3.z, a3.z); a3.w = fmaf(al, v3.w, a3.w);
    }
    float* dst = &wxtp[b * 4096 + k * 64 + g4 * 16];
    *(float4*)&dst[0] = a0;
    *(float4*)&dst[4] = a1;
    *(float4*)&dst[8] = a2;
    *(float4*)&dst[12] = a3;
}

// ---------------------------------------------------------------------------
// per step: z = sigmoid(wxt_c + conv(h,U_z)); r = sigmoid(wxt_c + conv(h,U_r));
// rh = r*h. block 64: thread = (k_local(8), y(8)). grid (8, 32)
__global__ __launch_bounds__(64) void k_step_zr(const float* __restrict__ Uz,
                                                const float* __restrict__ Ur,
                                                float* __restrict__ ws) {
    __shared__ float h_s[4096];
    __shared__ float wz_s[8 * 576];
    __shared__ float wr_s[8 * 576];
    const int b = blockIdx.y;
    const int k0 = blockIdx.x * 8;
    const int tid = threadIdx.x;
    const int kl = tid >> 3, y = tid & 7;
#pragma unroll
    for (int i = 0; i < 16; ++i) {
        int f = tid + i * 64;
        *(float4*)&h_s[f * 4] = *(const float4*)&ws[H_OFF + b * 4096 + f * 4];
    }
#pragma unroll
    for (int i = 0; i < 18; ++i) {
        int f = tid + i * 64;
        *(float4*)&wz_s[f * 4] = *(const float4*)&Uz[k0 * 576 + f * 4];
        *(float4*)&wr_s[f * 4] = *(const float4*)&Ur[k0 * 576 + f * 4];
    }
    __syncthreads();
    float cz[8], cr[8];
#pragma unroll
    for (int xx = 0; xx < 8; ++xx) { cz[xx] = 0.f; cr[xx] = 0.f; }
    for (int kp = 0; kp < 64; ++kp) {
        const float* wpz = &wz_s[kl * 576 + kp * 9];
        const float* wpr = &wr_s[kl * 576 + kp * 9];
        float wz[9], wr[9];
#pragma unroll
        for (int q = 0; q < 9; ++q) { wz[q] = wpz[q]; wr[q] = wpr[q]; }
#pragma unroll
        for (int dy = 0; dy < 3; ++dy) {
            int yy = y + dy - 1;
            if (yy >= 0 && yy < 8) {
                float4 ra = *(const float4*)&h_s[kp * 64 + yy * 8];
                float4 rb = *(const float4*)&h_s[kp * 64 + yy * 8 + 4];
                float r[8] = {ra.x, ra.y, ra.z, ra.w, rb.x, rb.y, rb.z, rb.w};
#pragma unroll
                for (int xx = 0; xx < 8; ++xx) {
                    float tz = wz[dy * 3 + 1] * r[xx];
                    float tr = wr[dy * 3 + 1] * r[xx];
                    if (xx > 0) { tz += wz[dy * 3] * r[xx - 1]; tr += wr[dy * 3] * r[xx - 1]; }
                    if (xx < 7) { tz += wz[dy * 3 + 2] * r[xx + 1]; tr += wr[dy * 3 + 2] * r[xx + 1]; }
                    cz[xx] += tz;
                    cr[xx] += tr;
                }
            }
        }
    }
    const int k = k0 + kl;
    const int base = b * 4096 + k * 64 + y * 8;
    const float* wxtc = ws + WXTC_OFF;
    float* zb = ws + Z_OFF;
    float* rhb = ws + RH_OFF;
    float4 wca = *(const float4*)&wxtc[base];
    float4 wcb = *(const float4*)&wxtc[base + 4];
    float wc8[8] = {wca.x, wca.y, wca.z, wca.w, wcb.x, wcb.y, wcb.z, wcb.w};
    float zo[8], ro[8];
#pragma unroll
    for (int xx = 0; xx < 8; ++xx) {
        zo[xx] = 1.f / (1.f + expf(-(wc8[xx] + cz[xx])));
        float rr = 1.f / (1.f + expf(-(wc8[xx] + cr[xx])));
        ro[xx] = rr * h_s[k * 64 + y * 8 + xx];
    }
    float4 z0 = {zo[0], zo[1], zo[2], zo[3]}, z1 = {zo[4], zo[5], zo[6], zo[7]};
    float4 r0 = {ro[0], ro[1], ro[2], ro[3]}, r1 = {ro[4], ro[5], ro[6], ro[7]};
    *(float4*)&zb[base] = z0;
    *(float4*)&zb[base + 4] = z1;
    *(float4*)&rhb[base] = r0;
    *(float4*)&rhb[base + 4] = r1;
}

// ---------------------------------------------------------------------------
// per step: hh = tanh(wxt_c + conv(rh,U_h)); h = (1-z)*hh + z*h; write hs, asum
__global__ __launch_bounds__(128) void k_step_hh(const float* __restrict__ Uh,
                                                 float* __restrict__ ws, int t) {
    __shared__ float in_s[4096];
    __shared__ float w_s[16 * 576];
    const int b = blockIdx.y;
    const int k0 = blockIdx.x * 16;
    const int tid = threadIdx.x;
    const int kl = tid >> 3, y = tid & 7;
#pragma unroll
    for (int i = 0; i < 8; ++i) {
        int f = tid + i * 128;
        *(float4*)&in_s[f * 4] = *(const float4*)&ws[RH_OFF + b * 4096 + f * 4];
    }
#pragma unroll
    for (int i = 0; i < 18; ++i) {
        int f = tid + i * 128;
        *(float4*)&w_s[f * 4] = *(const float4*)&Uh[k0 * 576 + f * 4];
    }
    __syncthreads();
    float ch[8];
#pragma unroll
    for (int xx = 0; xx < 8; ++xx) ch[xx] = 0.f;
    for (int kp = 0; kp < 64; ++kp) {
        const float* wp = &w_s[kl * 576 + kp * 9];
        float wv[9];
#pragma unroll
        for (int q = 0; q < 9; ++q) wv[q] = wp[q];
#pragma unroll
        for (int dy = 0; dy < 3; ++dy) {
            int yy = y + dy - 1;
            if (yy >= 0 && yy < 8) {
                float4 ra = *(const float4*)&in_s[kp * 64 + yy * 8];
                float4 rb = *(const float4*)&in_s[kp * 64 + yy * 8 + 4];
                float r[8] = {ra.x, ra.y, ra.z, ra.w, rb.x, rb.y, rb.z, rb.w};
                float wa = wv[dy * 3 + 0], wb = wv[dy * 3 + 1], wc = wv[dy * 3 + 2];
#pragma unroll
                for (int xx = 0; xx < 8; ++xx) {
                    float tt = wb * r[xx];
                    if (xx > 0) tt += wa * r[xx - 1];
                    if (xx < 7) tt += wc * r[xx + 1];
                    ch[xx] += tt;
                }
            }
        }
    }
    const int k = k0 + kl;
    const int base = b * 4096 + k * 64 + y * 8;
    const float* wxtc = ws + WXTC_OFF;
    const float* zb = ws + Z_OFF;
    float* h = ws + H_OFF;
    float* hs = ws + HS_OFF;
    float4 wca = *(const float4*)&wxtc[base];
    float4 wcb = *(const float4*)&wxtc[base + 4];
    float4 za = *(const float4*)&zb[base];
    float4 zb4 = *(const float4*)&zb[base + 4];
    float4 ha = *(const float4*)&h[base];
    float4 hb = *(const float4*)&h[base + 4];
    float wc8[8] = {wca.x, wca.y, wca.z, wca.w, wcb.x, wcb.y, wcb.z, wcb.w};
    float z8[8] = {za.x, za.y, za.z, za.w, zb4.x, zb4.y, zb4.z, zb4.w};
    float h8[8] = {ha.x, ha.y, ha.z, ha.w, hb.x, hb.y, hb.z, hb.w};
    float hn[8];
    float s = 0.f;
#pragma unroll
    for (int xx = 0; xx < 8; ++xx) {
        float hh = tanhf(wc8[xx] + ch[xx]);
        hn[xx] = (1.f - z8[xx]) * hh + z8[xx] * h8[xx];
        s += hn[xx];
    }
    float4 o0 = {hn[0], hn[1], hn[2], hn[3]}, o1 = {hn[4], hn[5], hn[6], hn[7]};
    *(float4*)&h[base] = o0;
    *(float4*)&h[base + 4] = o1;
    int hsbase = ((t * 32 + b) * 64 + k) * 64 + y * 8;
    *(float4*)&hs[hsbase] = o0;
    *(float4*)&hs[hsbase + 4] = o1;
    s += __shfl_down(s, 4, 8);
    s += __shfl_down(s, 2, 8);
    s += __shfl_down(s, 1, 8);
    if (y == 0) ws[ASUM_OFF + b * 512 + t * 64 + k] = s;
}

// ---------------------------------------------------------------------------
// VLAD: V[b,k,d] = sum_{t,hw} hs*xt - (sum_t asum)*centers. grid (8,32), 256 thr
__global__ __launch_bounds__(256) void k_vlad(const float* __restrict__ centers,
                                              const float* __restrict__ ws,
                                              float* __restrict__ out) {
    __shared__ float As[16 * 68];
    __shared__ float Bs[16 * 68];
    const int b = blockIdx.y;
    const int d0 = blockIdx.x * 64;
    const int tid = threadIdx.x;
    const int kq = tid & 15, dq = tid >> 4;
    const int lk = tid >> 2, q = tid & 3;
    const float* hs = ws + HS_OFF;
    const float* xt = ws + XT_OFF;
    float acc[4][4];
#pragma unroll
    for (int i = 0; i < 4; ++i)
#pragma unroll
        for (int j = 0; j < 4; ++j) acc[i][j] = 0.f;

    for (int rc = 0; rc < 512; rc += 16) {
        int t = rc >> 6, hw0 = rc & 63;
        float4 va = *(const float4*)&hs[((t * 32 + b) * 64 + lk) * 64 + hw0 + q * 4];
        float4 vb = *(const float4*)&xt[(b * 8 + t) * 32768 + (d0 + lk) * 64 + hw0 + q * 4];
        __syncthreads();
        As[(q * 4 + 0) * 68 + lk] = va.x;
        As[(q * 4 + 1) * 68 + lk] = va.y;
        As[(q * 4 + 2) * 68 + lk] = va.z;
        As[(q * 4 + 3) * 68 + lk] = va.w;
        Bs[(q * 4 + 0) * 68 + lk] = vb.x;
        Bs[(q * 4 + 1) * 68 + lk] = vb.y;
        Bs[(q * 4 + 2) * 68 + lk] = vb.z;
        Bs[(q * 4 + 3) * 68 + lk] = vb.w;
        __syncthreads();
#pragma unroll
        for (int cc = 0; cc < 16; ++cc) {
            float4 a = *(const float4*)&As[cc * 68 + kq * 4];
            float4 bb = *(const float4*)&Bs[cc * 68 + dq * 4];
            float av[4] = {a.x, a.y, a.z, a.w};
            float bv[4] = {bb.x, bb.y, bb.z, bb.w};
#pragma unroll
            for (int i = 0; i < 4; ++i)
#pragma unroll
                for (int j = 0; j < 4; ++j)
                    acc[i][j] = fmaf(av[i], bv[j], acc[i][j]);
        }
    }
    const float* asum = ws + ASUM_OFF;
#pragma unroll
    for (int i = 0; i < 4; ++i) {
        int k = kq * 4 + i;
        float at = 0.f;
#pragma unroll
        for (int tp = 0; tp < 8; ++tp) at += asum[b * 512 + tp * 64 + k];
        float4 cen = *(const float4*)&centers[k * 512 + d0 + dq * 4];
        float4 o = {acc[i][0] - at * cen.x, acc[i][1] - at * cen.y,
                    acc[i][2] - at * cen.z, acc[i][3] - at * cen.w};
        *(float4*)&out[b * 32768 + k * 512 + d0 + dq * 4] = o;
    }
}

// ---------------------------------------------------------------------------
__global__ __launch_bounds__(64) void k_norm1(float* __restrict__ out) {
    const int b = blockIdx.x >> 6, k = blockIdx.x & 63;
    float* p = out + b * 32768 + k * 512;
    const int tid = threadIdx.x;
    float v[8];
    float ss = 0.f;
#pragma unroll
    for (int i = 0; i < 8; ++i) {
        v[i] = p[tid + i * 64];
        ss = fmaf(v[i], v[i], ss);
    }
#pragma unroll
    for (int off = 32; off > 0; off >>= 1) ss += __shfl_down(ss, off, 64);
    ss = __shfl(ss, 0, 64);
    float sc = 1.f / fmaxf(sqrtf(ss), 1e-12f);
#pragma unroll
    for (int i = 0; i < 8; ++i) p[tid + i * 64] = v[i] * sc;
}

__global__ __launch_bounds__(256) void k_norm2(float* __restrict__ out) {
    __shared__ float red[4];
    __shared__ float stot;
    const int b = blockIdx.x;
    const int tid = threadIdx.x;
    float* p = out + b * 32768;
    float ss = 0.f;
    for (int i = 0; i < 32; ++i) {
        float4 v = *(const float4*)&p[tid * 4 + i * 1024];
        ss += v.x * v.x + v.y * v.y + v.z * v.z + v.w * v.w;
    }
#pragma unroll
    for (int off = 32; off > 0; off >>= 1) ss += __shfl_down(ss, off, 64);
    if ((tid & 63) == 0) red[tid >> 6] = ss;
    __syncthreads();
    if (tid == 0) stot = 1.f / fmaxf(sqrtf(red[0] + red[1] + red[2] + red[3]), 1e-12f);
    __syncthreads();
    float sc = stot;
    for (int i = 0; i < 32; ++i) {
        float4 v = *(const float4*)&p[tid * 4 + i * 1024];
        v.x *= sc; v.y *= sc; v.z *= sc; v.w *= sc;
        *(float4*)&p[tid * 4 + i * 1024] = v;
    }
}

// ---------------------------------------------------------------------------
extern "C" void kernel_launch(void* const* d_in, const int* in_sizes, int n_in,
                              void* d_out, int out_size, void* d_ws, size_t ws_size,
                              hipStream_t stream) {
    const float* x       = (const float*)d_in[0];
    const float* redu_w  = (const float*)d_in[1];
    const float* redu_b  = (const float*)d_in[2];
    const float* w_x     = (const float*)d_in[3];
    const float* att_x   = (const float*)d_in[4];
    const float* att_h_w = (const float*)d_in[5];
    const float* att_b   = (const float*)d_in[6];
    const float* share_w = (const float*)d_in[7];
    const float* share_b = (const float*)d_in[8];
    const float* U_r     = (const float*)d_in[9];
    const float* U_z     = (const float*)d_in[10];
    const float* U_h     = (const float*)d_in[11];
    const float* centers = (const float*)d_in[12];
    const float* fc1_w   = (const float*)d_in[13];
    const float* fc2_w   = (const float*)d_in[14];
    float* ws = (float*)d_ws;
    float* out = (float*)d_out;

    k_prep<<<dim3(3712), dim3(256), 0, stream>>>(redu_w, w_x, ws);
    k_gemm_xt<<<dim3(2, 256), dim3(256), 0, stream>>>(x, redu_b, ws);
    k_gemm_wxpb<<<dim3(256), dim3(256), 0, stream>>>(ws);
    k_conv3x3<<<dim3(4, 256), dim3(128), 0, stream>>>(ws + WXPB_OFF, att_x,
                                                      (const float*)nullptr, ws + ATTV_OFF);
    for (int t = 0; t < 8; ++t) {
        k_step_ah_e<<<dim3(4, 32), dim3(128), 0, stream>>>(att_h_w, att_b, ws);
        k_step_fc<<<dim3(32), dim3(256), 0, stream>>>(fc1_w, fc2_w, ws);
        k_conv3x3<<<dim3(4, 32), dim3(128), 0, stream>>>(ws + WXTP_OFF, share_w,
                                                         share_b, ws + WXTC_OFF);
        k_step_zr<<<dim3(8, 32), dim3(64), 0, stream>>>(U_z, U_r, ws);
        k_step_hh<<<dim3(4, 32), dim3(128), 0, stream>>>(U_h, ws, t);
    }
    k_vlad<<<dim3(8, 32), dim3(256), 0, stream>>>(centers, ws, out);
    k_norm1<<<dim3(2048), dim3(64), 0, stream>>>(out);
    k_norm2<<<dim3(32), dim3(256), 0, stream>>>(out);
}

// Round 2
// 1425.060 us; speedup vs baseline: 1.0860x; 1.0860x over previous
//
#include <hip/hip_runtime.h>
#include <math.h>

// Problem constants
#define T_   8
#define K_   64
#define D_   512
#define CIN_ 1536
#define B_   32
#define S_   64    // H*W = 8*8
#define NT_  256   // B*T

// Workspace layout (float offsets)
// WHI/WLO: bf16 [512][1536] hi/lo split of redu_w (occupies old Wt region)
#define WLO_BF16  786432u     // bf16-element offset of Wlo within bf16 view
#define WXT_OFF   786432u     // [512][64]  transposed w_x (float offset)
#define XT_OFF    819200u     // [256][512][64]
#define WXPB_OFF  9207808u    // [256][64][64]
#define ATTV_OFF  10256384u   // [256][64][64]  (n = b*8+t)
#define H_OFF     11304960u   // [32][64][64]
#define HS_OFF    11436032u   // [8][32][64][64]
#define WXTP_OFF  12517376u   // [32][64][64]
#define WXTC_OFF  12648448u   // [32][64][64]
#define Z_OFF     12779520u   // [32][64][64]
#define RH_OFF    12910592u   // [32][64][64]
#define ASUM_OFF  13041664u   // [32][8][64]

typedef __bf16 v8bf __attribute__((ext_vector_type(8)));
typedef __bf16 v4bf __attribute__((ext_vector_type(4)));
typedef float  v4f  __attribute__((ext_vector_type(4)));

// ---------------------------------------------------------------------------
// prep: split redu_w -> bf16 hi/lo, transpose w_x -> wxT[d][k], zero h
__global__ __launch_bounds__(256) void k_prep(const float* __restrict__ redu_w,
                                              const float* __restrict__ w_x,
                                              float* __restrict__ ws) {
    unsigned idx = blockIdx.x * 256u + threadIdx.x;
    if (idx < 786432u) {
        float f = redu_w[idx];
        __bf16 h = (__bf16)f;
        __bf16 l = (__bf16)(f - (float)h);
        __bf16* wb = (__bf16*)ws;
        wb[idx] = h;
        wb[WLO_BF16 + idx] = l;
    } else if (idx < 819200u) {
        unsigned i = idx - 786432u;
        unsigned dd = i >> 6, k = i & 63u;
        ws[WXT_OFF + i] = w_x[k * 512u + dd];
    } else if (idx < 950272u) {
        ws[H_OFF + (idx - 819200u)] = 0.f;
    }
}

// ---------------------------------------------------------------------------
// xt = redu_w @ x + redu_b via bf16 hi/lo split MFMA (3 products).
// grid (2, 256): d0 = blockIdx.x*256, n = blockIdx.y. block 256 = 4 waves.
// Wave w: m-range d0+w*64..+63 (4 m-tiles of 16) x full 64 s (4 n-tiles).
__global__ __launch_bounds__(256) void k_gemm_xt_mfma(const float* __restrict__ x,
                                                      const float* __restrict__ redu_b,
                                                      float* __restrict__ ws) {
    __shared__ __bf16 xhi_s[64 * 72];   // [s][k+pad8], 16B-aligned rows (144B)
    __shared__ __bf16 xlo_s[64 * 72];
    const __bf16* __restrict__ Whi = (const __bf16*)ws;
    const __bf16* __restrict__ Wlo = ((const __bf16*)ws) + WLO_BF16;
    float* xt = ws + XT_OFF;
    const int n = blockIdx.y;
    const int d0 = blockIdx.x * 256;
    const int tid = threadIdx.x;
    const int wave = tid >> 6, lane = tid & 63;
    const int lrow = lane & 15, lkg = lane >> 4;
    const int m_base = d0 + wave * 64;
    const float* __restrict__ xn = x + n * 98304;
    const int s4 = tid & 15, cb = tid >> 4;   // staging: 4s x 4c block per thread

    v4f acc[4][4];
#pragma unroll
    for (int mt = 0; mt < 4; ++mt)
#pragma unroll
        for (int nt = 0; nt < 4; ++nt) acc[mt][nt] = (v4f){0.f, 0.f, 0.f, 0.f};

    for (int c0 = 0; c0 < 1536; c0 += 64) {
        // load x block: c = c0+cb*4+j, s = s4*4+i  (wave-coalesced float4)
        float4 v[4];
#pragma unroll
        for (int j = 0; j < 4; ++j)
            v[j] = *(const float4*)&xn[(c0 + cb * 4 + j) * 64 + s4 * 4];
        __syncthreads();
#pragma unroll
        for (int i = 0; i < 4; ++i) {
            v4bf hv, lv;
#pragma unroll
            for (int j = 0; j < 4; ++j) {
                float f = ((const float*)&v[j])[i];
                __bf16 h = (__bf16)f;
                hv[j] = h;
                lv[j] = (__bf16)(f - (float)h);
            }
            int row = s4 * 4 + i;
            *(v4bf*)&xhi_s[row * 72 + cb * 4] = hv;
            *(v4bf*)&xlo_s[row * 72 + cb * 4] = lv;
        }
        __syncthreads();
#pragma unroll
        for (int ks = 0; ks < 64; ks += 32) {
            v8bf bh[4], bl[4], ah[4], al[4];
#pragma unroll
            for (int nt = 0; nt < 4; ++nt) {
                int off = (nt * 16 + lrow) * 72 + ks + lkg * 8;
                bh[nt] = *(const v8bf*)&xhi_s[off];
                bl[nt] = *(const v8bf*)&xlo_s[off];
            }
#pragma unroll
            for (int mt = 0; mt < 4; ++mt) {
                int gi = (m_base + mt * 16 + lrow) * 1536 + c0 + ks + lkg * 8;
                ah[mt] = *(const v8bf*)&Whi[gi];
                al[mt] = *(const v8bf*)&Wlo[gi];
            }
#pragma unroll
            for (int mt = 0; mt < 4; ++mt)
#pragma unroll
                for (int nt = 0; nt < 4; ++nt) {
                    acc[mt][nt] = __builtin_amdgcn_mfma_f32_16x16x32_bf16(
                        ah[mt], bh[nt], acc[mt][nt], 0, 0, 0);
                    acc[mt][nt] = __builtin_amdgcn_mfma_f32_16x16x32_bf16(
                        ah[mt], bl[nt], acc[mt][nt], 0, 0, 0);
                    acc[mt][nt] = __builtin_amdgcn_mfma_f32_16x16x32_bf16(
                        al[mt], bh[nt], acc[mt][nt], 0, 0, 0);
                }
        }
    }
    // epilogue: C row=(lane>>4)*4+reg, col=lane&15
#pragma unroll
    for (int mt = 0; mt < 4; ++mt) {
#pragma unroll
        for (int r = 0; r < 4; ++r) {
            int m = m_base + mt * 16 + lkg * 4 + r;
            float bias = redu_b[m];
#pragma unroll
            for (int nt = 0; nt < 4; ++nt) {
                int s = nt * 16 + lrow;
                xt[(n * 512 + m) * 64 + s] = acc[mt][nt][r] + bias;
            }
        }
    }
}

// ---------------------------------------------------------------------------
// wxpb = w_x @ xt ; per n: (64x512)@(512x64). grid 256, block 256, 4x4/thread.
__global__ __launch_bounds__(256) void k_gemm_wxpb(float* __restrict__ ws) {
    __shared__ float Aw[16 * 64];
    __shared__ float Bx[16 * 64];
    const float* wxT = ws + WXT_OFF;
    const float* xt = ws + XT_OFF;
    float* wxpb = ws + WXPB_OFF;
    const int n = blockIdx.x;
    const int tid = threadIdx.x;
    const int sg = tid & 15, kg = tid >> 4;

    float acc[4][4];
#pragma unroll
    for (int i = 0; i < 4; ++i)
#pragma unroll
        for (int j = 0; j < 4; ++j) acc[i][j] = 0.f;

    for (int d0 = 0; d0 < 512; d0 += 16) {
        int cc = tid >> 4, q = tid & 15;
        *(float4*)&Aw[cc * 64 + q * 4] = *(const float4*)&wxT[(d0 + cc) * 64 + q * 4];
        *(float4*)&Bx[cc * 64 + q * 4] = *(const float4*)&xt[n * 32768 + (d0 + cc) * 64 + q * 4];
        __syncthreads();
#pragma unroll
        for (int c2 = 0; c2 < 16; ++c2) {
            float4 a = *(const float4*)&Aw[c2 * 64 + kg * 4];
            float4 b = *(const float4*)&Bx[c2 * 64 + sg * 4];
            float av[4] = {a.x, a.y, a.z, a.w};
            float bv[4] = {b.x, b.y, b.z, b.w};
#pragma unroll
            for (int i = 0; i < 4; ++i)
#pragma unroll
                for (int j = 0; j < 4; ++j)
                    acc[i][j] = fmaf(av[i], bv[j], acc[i][j]);
        }
        __syncthreads();
    }
#pragma unroll
    for (int i = 0; i < 4; ++i) {
        float4 o = {acc[i][0], acc[i][1], acc[i][2], acc[i][3]};
        *(float4*)&wxpb[(n * 64 + kg * 4 + i) * 64 + sg * 4] = o;
    }
}

// ---------------------------------------------------------------------------
// generic 3x3 conv, pad=1, 64->16 channels per block (grid.x=4), one image per
// blockIdx.y. block 128: thread = (k_local(16), y(8)), 8 x-outputs in regs.
__global__ __launch_bounds__(128) void k_conv3x3(const float* __restrict__ in,
                                                 const float* __restrict__ wt,
                                                 const float* __restrict__ bias,
                                                 float* __restrict__ out) {
    __shared__ float in_s[4096];
    __shared__ float w_s[16 * 576];
    const int img = blockIdx.y;
    const int k0 = blockIdx.x * 16;
    const int tid = threadIdx.x;
    const int kl = tid >> 3, y = tid & 7;
#pragma unroll
    for (int i = 0; i < 8; ++i) {
        int f = tid + i * 128;
        *(float4*)&in_s[f * 4] = *(const float4*)&in[img * 4096 + f * 4];
    }
#pragma unroll
    for (int i = 0; i < 18; ++i) {
        int f = tid + i * 128;
        *(float4*)&w_s[f * 4] = *(const float4*)&wt[k0 * 576 + f * 4];
    }
    __syncthreads();
    float o[8];
#pragma unroll
    for (int xx = 0; xx < 8; ++xx) o[xx] = 0.f;
    for (int kp = 0; kp < 64; ++kp) {
        const float* wp = &w_s[kl * 576 + kp * 9];
        float wv[9];
#pragma unroll
        for (int q = 0; q < 9; ++q) wv[q] = wp[q];
#pragma unroll
        for (int dy = 0; dy < 3; ++dy) {
            int yy = y + dy - 1;
            if (yy >= 0 && yy < 8) {
                float4 ra = *(const float4*)&in_s[kp * 64 + yy * 8];
                float4 rb = *(const float4*)&in_s[kp * 64 + yy * 8 + 4];
                float r[8] = {ra.x, ra.y, ra.z, ra.w, rb.x, rb.y, rb.z, rb.w};
                float wa = wv[dy * 3 + 0], wb = wv[dy * 3 + 1], wc = wv[dy * 3 + 2];
#pragma unroll
                for (int xx = 0; xx < 8; ++xx) {
                    float t = wb * r[xx];
                    if (xx > 0) t += wa * r[xx - 1];
                    if (xx < 7) t += wc * r[xx + 1];
                    o[xx] += t;
                }
            }
        }
    }
    float bv = bias ? bias[k0 + kl] : 0.f;
    float4 o0 = {o[0] + bv, o[1] + bv, o[2] + bv, o[3] + bv};
    float4 o1 = {o[4] + bv, o[5] + bv, o[6] + bv, o[7] + bv};
    *(float4*)&out[img * 4096 + (k0 + kl) * 64 + y * 8] = o0;
    *(float4*)&out[img * 4096 + (k0 + kl) * 64 + y * 8 + 4] = o1;
}

// ---------------------------------------------------------------------------
// Fused per-step kernel A: ah = conv(h,att_h_w)+att_b; e = relu(attv+ah);
// emean/emax (LDS); channel-attention MLP; softmax over T; wxtp = sum_t a*wxpb.
// grid 32 (b), block 512 = (k(64), y(8)). Weights staged in 4 kp-passes.
__global__ __launch_bounds__(512) void k_stepA(const float* __restrict__ att_h_w,
                                               const float* __restrict__ att_b,
                                               const float* __restrict__ fc1_w,
                                               const float* __restrict__ fc2_w,
                                               float* __restrict__ ws) {
    __shared__ float h_s[4096];
    __shared__ float w_s[64 * 146];   // [k][144 + 2 pad]
    __shared__ float em[512], ex[512], h1[64], exs[512], als[512];
    const int b = blockIdx.x;
    const int tid = threadIdx.x;
    const int k = tid >> 3, y = tid & 7;
    const int th = tid & 7;

    // stage h
#pragma unroll
    for (int i = 0; i < 2; ++i) {
        int f = tid + i * 512;
        *(float4*)&h_s[f * 4] = *(const float4*)&ws[H_OFF + b * 4096 + f * 4];
    }
    float ah[8];
#pragma unroll
    for (int xx = 0; xx < 8; ++xx) ah[xx] = 0.f;

    for (int p = 0; p < 4; ++p) {
        __syncthreads();
        // stage att_h_w[k][kp=p*16..+15][9] = 144 floats/k; 8 threads per k
#pragma unroll
        for (int i = 0; i < 9; ++i) {
            int j2 = th + i * 8;
            *(float2*)&w_s[k * 146 + j2 * 2] =
                *(const float2*)&att_h_w[k * 576 + p * 144 + j2 * 2];
        }
        __syncthreads();
        for (int kpl = 0; kpl < 16; ++kpl) {
            int kp = p * 16 + kpl;
            const float* wp = &w_s[k * 146 + kpl * 9];
            float wv[9];
#pragma unroll
            for (int q = 0; q < 9; ++q) wv[q] = wp[q];
#pragma unroll
            for (int dy = 0; dy < 3; ++dy) {
                int yy = y + dy - 1;
                if (yy >= 0 && yy < 8) {
                    float4 ra = *(const float4*)&h_s[kp * 64 + yy * 8];
                    float4 rb = *(const float4*)&h_s[kp * 64 + yy * 8 + 4];
                    float r[8] = {ra.x, ra.y, ra.z, ra.w, rb.x, rb.y, rb.z, rb.w};
                    float wa = wv[dy * 3 + 0], wb = wv[dy * 3 + 1], wc = wv[dy * 3 + 2];
#pragma unroll
                    for (int xx = 0; xx < 8; ++xx) {
                        float t = wb * r[xx];
                        if (xx > 0) t += wa * r[xx - 1];
                        if (xx < 7) t += wc * r[xx + 1];
                        ah[xx] += t;
                    }
                }
            }
        }
    }
    const float ab = att_b[k];
#pragma unroll
    for (int xx = 0; xx < 8; ++xx) ah[xx] += ab;

    // e = relu(attv + ah); reduce mean/max over hw -> LDS
    const float* attv = ws + ATTV_OFF;
    for (int tp = 0; tp < 8; ++tp) {
        const float* av = &attv[((b * 8 + tp) * 64 + k) * 64 + y * 8];
        float4 va = *(const float4*)&av[0];
        float4 vb = *(const float4*)&av[4];
        float e[8] = {va.x, va.y, va.z, va.w, vb.x, vb.y, vb.z, vb.w};
        float s = 0.f, m = 0.f;
#pragma unroll
        for (int xx = 0; xx < 8; ++xx) {
            float v = fmaxf(e[xx] + ah[xx], 0.f);
            s += v;
            m = fmaxf(m, v);
        }
        s += __shfl_down(s, 4, 8);
        s += __shfl_down(s, 2, 8);
        s += __shfl_down(s, 1, 8);
        m = fmaxf(m, __shfl_down(m, 4, 8));
        m = fmaxf(m, __shfl_down(m, 2, 8));
        m = fmaxf(m, __shfl_down(m, 1, 8));
        if (y == 0) {
            em[tp * 64 + k] = s * (1.f / 64.f);
            ex[tp * 64 + k] = m;
        }
    }
    __syncthreads();
    // fc1: slot i2 = tid>>3 (0..63: 0-31 mean, 32-63 max), 8 parts of 64 c
    {
        int i2 = tid >> 3, part = tid & 7;
        int i = i2 & 31;
        const float* src = (i2 < 32) ? em : ex;
        const float* wrow = fc1_w + i * 512 + part * 64;
        const float* s2 = src + part * 64;
        float p = 0.f;
        for (int c = 0; c < 64; ++c) p = fmaf(wrow[c], s2[c], p);
        p += __shfl_down(p, 4, 8);
        p += __shfl_down(p, 2, 8);
        p += __shfl_down(p, 1, 8);
        if (part == 0) h1[i2] = fmaxf(p, 0.f);
    }
    __syncthreads();
    // fc2 + tanh + exp: j = tid (512)
    {
        const float* w2 = fc2_w + tid * 32;
        float gm = 0.f, gx = 0.f;
#pragma unroll
        for (int i = 0; i < 32; ++i) {
            gm = fmaf(w2[i], h1[i], gm);
            gx = fmaf(w2[i], h1[32 + i], gx);
        }
        exs[tid] = expf(tanhf(gm + gx));
    }
    __syncthreads();
    {
        int kk = tid & 63;
        float den = 0.f;
#pragma unroll
        for (int tp = 0; tp < 8; ++tp) den += exs[tp * 64 + kk];
        den += (den == 0.f) ? 1.f : 0.f;
        als[tid] = exs[tid] / den;
    }
    __syncthreads();
    // wxtp = sum_t alpha * wxpb : thread (k, y) handles s = y*8..+7
    {
        const float* wxpb = ws + WXPB_OFF;
        float* wxtp = ws + WXTP_OFF;
        float a0[8];
#pragma unroll
        for (int xx = 0; xx < 8; ++xx) a0[xx] = 0.f;
        for (int tp = 0; tp < 8; ++tp) {
            float al = als[tp * 64 + k];
            const float* src = &wxpb[((b * 8 + tp) * 64 + k) * 64 + y * 8];
            float4 v0 = *(const float4*)&src[0];
            float4 v1 = *(const float4*)&src[4];
            float v[8] = {v0.x, v0.y, v0.z, v0.w, v1.x, v1.y, v1.z, v1.w};
#pragma unroll
            for (int xx = 0; xx < 8; ++xx) a0[xx] = fmaf(al, v[xx], a0[xx]);
        }
        float4 o0 = {a0[0], a0[1], a0[2], a0[3]};
        float4 o1 = {a0[4], a0[5], a0[6], a0[7]};
        *(float4*)&wxtp[b * 4096 + k * 64 + y * 8] = o0;
        *(float4*)&wxtp[b * 4096 + k * 64 + y * 8 + 4] = o1;
    }
}

// ---------------------------------------------------------------------------
// Fused per-step kernel B: wxtc = conv(wxtp, share_w)+share_b;
// z = sigmoid(wxtc + conv(h,U_z)); r = sigmoid(wxtc + conv(h,U_r)); rh = r*h.
// grid (4, 32), block 128 = (kl(16), y(8)). Weights staged in 4 kp-passes.
__global__ __launch_bounds__(128) void k_stepB(const float* __restrict__ Uz,
                                               const float* __restrict__ Ur,
                                               const float* __restrict__ share_w,
                                               const float* __restrict__ share_b,
                                               float* __restrict__ ws) {
    __shared__ float h_s[4096];
    __shared__ float p_s[4096];
    __shared__ float wz_s[16 * 146];
    __shared__ float wr_s[16 * 146];
    __shared__ float wsh_s[16 * 146];
    const int b = blockIdx.y;
    const int k0 = blockIdx.x * 16;
    const int tid = threadIdx.x;
    const int kl = tid >> 3, y = tid & 7;
    const int th = tid & 7;
#pragma unroll
    for (int i = 0; i < 8; ++i) {
        int f = tid + i * 128;
        *(float4*)&h_s[f * 4] = *(const float4*)&ws[H_OFF + b * 4096 + f * 4];
        *(float4*)&p_s[f * 4] = *(const float4*)&ws[WXTP_OFF + b * 4096 + f * 4];
    }
    float cz[8], cr[8], csh[8];
#pragma unroll
    for (int xx = 0; xx < 8; ++xx) { cz[xx] = 0.f; cr[xx] = 0.f; csh[xx] = 0.f; }

    for (int p = 0; p < 4; ++p) {
        __syncthreads();
#pragma unroll
        for (int i = 0; i < 9; ++i) {
            int j2 = th + i * 8;
            *(float2*)&wz_s[kl * 146 + j2 * 2] =
                *(const float2*)&Uz[(k0 + kl) * 576 + p * 144 + j2 * 2];
            *(float2*)&wr_s[kl * 146 + j2 * 2] =
                *(const float2*)&Ur[(k0 + kl) * 576 + p * 144 + j2 * 2];
            *(float2*)&wsh_s[kl * 146 + j2 * 2] =
                *(const float2*)&share_w[(k0 + kl) * 576 + p * 144 + j2 * 2];
        }
        __syncthreads();
        for (int kpl = 0; kpl < 16; ++kpl) {
            int kp = p * 16 + kpl;
            float wz[9], wr[9], wsh[9];
#pragma unroll
            for (int q = 0; q < 9; ++q) {
                wz[q] = wz_s[kl * 146 + kpl * 9 + q];
                wr[q] = wr_s[kl * 146 + kpl * 9 + q];
                wsh[q] = wsh_s[kl * 146 + kpl * 9 + q];
            }
#pragma unroll
            for (int dy = 0; dy < 3; ++dy) {
                int yy = y + dy - 1;
                if (yy >= 0 && yy < 8) {
                    float4 ha = *(const float4*)&h_s[kp * 64 + yy * 8];
                    float4 hb = *(const float4*)&h_s[kp * 64 + yy * 8 + 4];
                    float4 pa = *(const float4*)&p_s[kp * 64 + yy * 8];
                    float4 pb = *(const float4*)&p_s[kp * 64 + yy * 8 + 4];
                    float hr[8] = {ha.x, ha.y, ha.z, ha.w, hb.x, hb.y, hb.z, hb.w};
                    float pr[8] = {pa.x, pa.y, pa.z, pa.w, pb.x, pb.y, pb.z, pb.w};
#pragma unroll
                    for (int xx = 0; xx < 8; ++xx) {
                        float tz = wz[dy * 3 + 1] * hr[xx];
                        float tr = wr[dy * 3 + 1] * hr[xx];
                        float ts = wsh[dy * 3 + 1] * pr[xx];
                        if (xx > 0) {
                            tz += wz[dy * 3] * hr[xx - 1];
                            tr += wr[dy * 3] * hr[xx - 1];
                            ts += wsh[dy * 3] * pr[xx - 1];
                        }
                        if (xx < 7) {
                            tz += wz[dy * 3 + 2] * hr[xx + 1];
                            tr += wr[dy * 3 + 2] * hr[xx + 1];
                            ts += wsh[dy * 3 + 2] * pr[xx + 1];
                        }
                        cz[xx] += tz;
                        cr[xx] += tr;
                        csh[xx] += ts;
                    }
                }
            }
        }
    }
    const int k = k0 + kl;
    const int base = b * 4096 + k * 64 + y * 8;
    const float sb = share_b[k];
    float* wxtc = ws + WXTC_OFF;
    float* zb = ws + Z_OFF;
    float* rhb = ws + RH_OFF;
    float wo[8], zo[8], ro[8];
#pragma unroll
    for (int xx = 0; xx < 8; ++xx) {
        wo[xx] = csh[xx] + sb;
        zo[xx] = 1.f / (1.f + expf(-(wo[xx] + cz[xx])));
        float rr = 1.f / (1.f + expf(-(wo[xx] + cr[xx])));
        ro[xx] = rr * h_s[k * 64 + y * 8 + xx];
    }
    float4 w0 = {wo[0], wo[1], wo[2], wo[3]}, w1 = {wo[4], wo[5], wo[6], wo[7]};
    float4 z0 = {zo[0], zo[1], zo[2], zo[3]}, z1 = {zo[4], zo[5], zo[6], zo[7]};
    float4 r0 = {ro[0], ro[1], ro[2], ro[3]}, r1 = {ro[4], ro[5], ro[6], ro[7]};
    *(float4*)&wxtc[base] = w0;
    *(float4*)&wxtc[base + 4] = w1;
    *(float4*)&zb[base] = z0;
    *(float4*)&zb[base + 4] = z1;
    *(float4*)&rhb[base] = r0;
    *(float4*)&rhb[base + 4] = r1;
}

// ---------------------------------------------------------------------------
// per step: hh = tanh(wxt_c + conv(rh,U_h)); h = (1-z)*hh + z*h; write hs, asum
__global__ __launch_bounds__(128) void k_step_hh(const float* __restrict__ Uh,
                                                 float* __restrict__ ws, int t) {
    __shared__ float in_s[4096];
    __shared__ float w_s[16 * 576];
    const int b = blockIdx.y;
    const int k0 = blockIdx.x * 16;
    const int tid = threadIdx.x;
    const int kl = tid >> 3, y = tid & 7;
#pragma unroll
    for (int i = 0; i < 8; ++i) {
        int f = tid + i * 128;
        *(float4*)&in_s[f * 4] = *(const float4*)&ws[RH_OFF + b * 4096 + f * 4];
    }
#pragma unroll
    for (int i = 0; i < 18; ++i) {
        int f = tid + i * 128;
        *(float4*)&w_s[f * 4] = *(const float4*)&Uh[k0 * 576 + f * 4];
    }
    __syncthreads();
    float ch[8];
#pragma unroll
    for (int xx = 0; xx < 8; ++xx) ch[xx] = 0.f;
    for (int kp = 0; kp < 64; ++kp) {
        const float* wp = &w_s[kl * 576 + kp * 9];
        float wv[9];
#pragma unroll
        for (int q = 0; q < 9; ++q) wv[q] = wp[q];
#pragma unroll
        for (int dy = 0; dy < 3; ++dy) {
            int yy = y + dy - 1;
            if (yy >= 0 && yy < 8) {
                float4 ra = *(const float4*)&in_s[kp * 64 + yy * 8];
                float4 rb = *(const float4*)&in_s[kp * 64 + yy * 8 + 4];
                float r[8] = {ra.x, ra.y, ra.z, ra.w, rb.x, rb.y, rb.z, rb.w};
                float wa = wv[dy * 3 + 0], wb = wv[dy * 3 + 1], wc = wv[dy * 3 + 2];
#pragma unroll
                for (int xx = 0; xx < 8; ++xx) {
                    float tt = wb * r[xx];
                    if (xx > 0) tt += wa * r[xx - 1];
                    if (xx < 7) tt += wc * r[xx + 1];
                    ch[xx] += tt;
                }
            }
        }
    }
    const int k = k0 + kl;
    const int base = b * 4096 + k * 64 + y * 8;
    const float* wxtc = ws + WXTC_OFF;
    const float* zb = ws + Z_OFF;
    float* h = ws + H_OFF;
    float* hs = ws + HS_OFF;
    float4 wca = *(const float4*)&wxtc[base];
    float4 wcb = *(const float4*)&wxtc[base + 4];
    float4 za = *(const float4*)&zb[base];
    float4 zb4 = *(const float4*)&zb[base + 4];
    float4 ha = *(const float4*)&h[base];
    float4 hb = *(const float4*)&h[base + 4];
    float wc8[8] = {wca.x, wca.y, wca.z, wca.w, wcb.x, wcb.y, wcb.z, wcb.w};
    float z8[8] = {za.x, za.y, za.z, za.w, zb4.x, zb4.y, zb4.z, zb4.w};
    float h8[8] = {ha.x, ha.y, ha.z, ha.w, hb.x, hb.y, hb.z, hb.w};
    float hn[8];
    float s = 0.f;
#pragma unroll
    for (int xx = 0; xx < 8; ++xx) {
        float hh = tanhf(wc8[xx] + ch[xx]);
        hn[xx] = (1.f - z8[xx]) * hh + z8[xx] * h8[xx];
        s += hn[xx];
    }
    float4 o0 = {hn[0], hn[1], hn[2], hn[3]}, o1 = {hn[4], hn[5], hn[6], hn[7]};
    *(float4*)&h[base] = o0;
    *(float4*)&h[base + 4] = o1;
    int hsbase = ((t * 32 + b) * 64 + k) * 64 + y * 8;
    *(float4*)&hs[hsbase] = o0;
    *(float4*)&hs[hsbase + 4] = o1;
    s += __shfl_down(s, 4, 8);
    s += __shfl_down(s, 2, 8);
    s += __shfl_down(s, 1, 8);
    if (y == 0) ws[ASUM_OFF + b * 512 + t * 64 + k] = s;
}

// ---------------------------------------------------------------------------
// VLAD: V[b,k,d] = sum_{t,hw} hs*xt - (sum_t asum)*centers. grid (8,32), 256 thr
__global__ __launch_bounds__(256) void k_vlad(const float* __restrict__ centers,
                                              const float* __restrict__ ws,
                                              float* __restrict__ out) {
    __shared__ float As[16 * 68];
    __shared__ float Bs[16 * 68];
    const int b = blockIdx.y;
    const int d0 = blockIdx.x * 64;
    const int tid = threadIdx.x;
    const int kq = tid & 15, dq = tid >> 4;
    const int lk = tid >> 2, q = tid & 3;
    const float* hs = ws + HS_OFF;
    const float* xt = ws + XT_OFF;
    float acc[4][4];
#pragma unroll
    for (int i = 0; i < 4; ++i)
#pragma unroll
        for (int j = 0; j < 4; ++j) acc[i][j] = 0.f;

    for (int rc = 0; rc < 512; rc += 16) {
        int t = rc >> 6, hw0 = rc & 63;
        float4 va = *(const float4*)&hs[((t * 32 + b) * 64 + lk) * 64 + hw0 + q * 4];
        float4 vb = *(const float4*)&xt[(b * 8 + t) * 32768 + (d0 + lk) * 64 + hw0 + q * 4];
        __syncthreads();
        As[(q * 4 + 0) * 68 + lk] = va.x;
        As[(q * 4 + 1) * 68 + lk] = va.y;
        As[(q * 4 + 2) * 68 + lk] = va.z;
        As[(q * 4 + 3) * 68 + lk] = va.w;
        Bs[(q * 4 + 0) * 68 + lk] = vb.x;
        Bs[(q * 4 + 1) * 68 + lk] = vb.y;
        Bs[(q * 4 + 2) * 68 + lk] = vb.z;
        Bs[(q * 4 + 3) * 68 + lk] = vb.w;
        __syncthreads();
#pragma unroll
        for (int cc = 0; cc < 16; ++cc) {
            float4 a = *(const float4*)&As[cc * 68 + kq * 4];
            float4 bb = *(const float4*)&Bs[cc * 68 + dq * 4];
            float av[4] = {a.x, a.y, a.z, a.w};
            float bv[4] = {bb.x, bb.y, bb.z, bb.w};
#pragma unroll
            for (int i = 0; i < 4; ++i)
#pragma unroll
                for (int j = 0; j < 4; ++j)
                    acc[i][j] = fmaf(av[i], bv[j], acc[i][j]);
        }
    }
    const float* asum = ws + ASUM_OFF;
#pragma unroll
    for (int i = 0; i < 4; ++i) {
        int k = kq * 4 + i;
        float at = 0.f;
#pragma unroll
        for (int tp = 0; tp < 8; ++tp) at += asum[b * 512 + tp * 64 + k];
        float4 cen = *(const float4*)&centers[k * 512 + d0 + dq * 4];
        float4 o = {acc[i][0] - at * cen.x, acc[i][1] - at * cen.y,
                    acc[i][2] - at * cen.z, acc[i][3] - at * cen.w};
        *(float4*)&out[b * 32768 + k * 512 + d0 + dq * 4] = o;
    }
}

// ---------------------------------------------------------------------------
__global__ __launch_bounds__(64) void k_norm1(float* __restrict__ out) {
    const int b = blockIdx.x >> 6, k = blockIdx.x & 63;
    float* p = out + b * 32768 + k * 512;
    const int tid = threadIdx.x;
    float v[8];
    float ss = 0.f;
#pragma unroll
    for (int i = 0; i < 8; ++i) {
        v[i] = p[tid + i * 64];
        ss = fmaf(v[i], v[i], ss);
    }
#pragma unroll
    for (int off = 32; off > 0; off >>= 1) ss += __shfl_down(ss, off, 64);
    ss = __shfl(ss, 0, 64);
    float sc = 1.f / fmaxf(sqrtf(ss), 1e-12f);
#pragma unroll
    for (int i = 0; i < 8; ++i) p[tid + i * 64] = v[i] * sc;
}

__global__ __launch_bounds__(256) void k_norm2(float* __restrict__ out) {
    __shared__ float red[4];
    __shared__ float stot;
    const int b = blockIdx.x;
    const int tid = threadIdx.x;
    float* p = out + b * 32768;
    float ss = 0.f;
    for (int i = 0; i < 32; ++i) {
        float4 v = *(const float4*)&p[tid * 4 + i * 1024];
        ss += v.x * v.x + v.y * v.y + v.z * v.z + v.w * v.w;
    }
#pragma unroll
    for (int off = 32; off > 0; off >>= 1) ss += __shfl_down(ss, off, 64);
    if ((tid & 63) == 0) red[tid >> 6] = ss;
    __syncthreads();
    if (tid == 0) stot = 1.f / fmaxf(sqrtf(red[0] + red[1] + red[2] + red[3]), 1e-12f);
    __syncthreads();
    float sc = stot;
    for (int i = 0; i < 32; ++i) {
        float4 v = *(const float4*)&p[tid * 4 + i * 1024];
        v.x *= sc; v.y *= sc; v.z *= sc; v.w *= sc;
        *(float4*)&p[tid * 4 + i * 1024] = v;
    }
}

// ---------------------------------------------------------------------------
extern "C" void kernel_launch(void* const* d_in, const int* in_sizes, int n_in,
                              void* d_out, int out_size, void* d_ws, size_t ws_size,
                              hipStream_t stream) {
    const float* x       = (const float*)d_in[0];
    const float* redu_w  = (const float*)d_in[1];
    const float* redu_b  = (const float*)d_in[2];
    const float* w_x     = (const float*)d_in[3];
    const float* att_x   = (const float*)d_in[4];
    const float* att_h_w = (const float*)d_in[5];
    const float* att_b   = (const float*)d_in[6];
    const float* share_w = (const float*)d_in[7];
    const float* share_b = (const float*)d_in[8];
    const float* U_r     = (const float*)d_in[9];
    const float* U_z     = (const float*)d_in[10];
    const float* U_h     = (const float*)d_in[11];
    const float* centers = (const float*)d_in[12];
    const float* fc1_w   = (const float*)d_in[13];
    const float* fc2_w   = (const float*)d_in[14];
    float* ws = (float*)d_ws;
    float* out = (float*)d_out;

    k_prep<<<dim3(3712), dim3(256), 0, stream>>>(redu_w, w_x, ws);
    k_gemm_xt_mfma<<<dim3(2, 256), dim3(256), 0, stream>>>(x, redu_b, ws);
    k_gemm_wxpb<<<dim3(256), dim3(256), 0, stream>>>(ws);
    k_conv3x3<<<dim3(4, 256), dim3(128), 0, stream>>>(ws + WXPB_OFF, att_x,
                                                      (const float*)nullptr, ws + ATTV_OFF);
    for (int t = 0; t < 8; ++t) {
        k_stepA<<<dim3(32), dim3(512), 0, stream>>>(att_h_w, att_b, fc1_w, fc2_w, ws);
        k_stepB<<<dim3(4, 32), dim3(128), 0, stream>>>(U_z, U_r, share_w, share_b, ws);
        k_step_hh<<<dim3(4, 32), dim3(128), 0, stream>>>(U_h, ws, t);
    }
    k_vlad<<<dim3(8, 32), dim3(256), 0, stream>>>(centers, ws, out);
    k_norm1<<<dim3(2048), dim3(64), 0, stream>>>(out);
    k_norm2<<<dim3(32), dim3(256), 0, stream>>>(out);
}

// Round 4
// 1189.400 us; speedup vs baseline: 1.3012x; 1.1981x over previous
//
#include <hip/hip_runtime.h>
#include <math.h>

// Problem constants
#define T_   8
#define K_   64
#define D_   512
#define CIN_ 1536
#define B_   32
#define S_   64    // H*W = 8*8
#define NT_  256   // B*T

// Workspace layout (float offsets)
#define WLO_BF16  786432u     // bf16-element offset of Wlo within bf16 view
#define WXT_OFF   786432u     // [512][64]  transposed w_x (float offset)
#define XT_OFF    819200u     // [256][512][64]
#define WXPB_OFF  9207808u    // [256][64][64]
#define ATTV_OFF  10256384u   // [256][64][64]  (n = b*8+t)
#define HS_OFF    11436032u   // [8][32][64][64]
#define ASUM_OFF  13041664u   // [32][8][64]
// conv-weight pack (bf16 elements): 5 weights x (hi 36864 + lo 36864),
// layout per weight: [dydx(9)][o(64)][i(64)].  Lives in old WXTP..RH region.
#define WPB       25034752u

typedef __bf16 v8bf __attribute__((ext_vector_type(8)));
typedef __bf16 v4bf __attribute__((ext_vector_type(4)));
typedef float  v4f  __attribute__((ext_vector_type(4)));

// ---------------------------------------------------------------------------
// prep: split redu_w -> bf16 hi/lo, transpose w_x -> wxT[d][k]
__global__ __launch_bounds__(256) void k_prep(const float* __restrict__ redu_w,
                                              const float* __restrict__ w_x,
                                              float* __restrict__ ws) {
    unsigned idx = blockIdx.x * 256u + threadIdx.x;
    if (idx < 786432u) {
        float f = redu_w[idx];
        __bf16 h = (__bf16)f;
        __bf16 l = (__bf16)(f - (float)h);
        __bf16* wb = (__bf16*)ws;
        wb[idx] = h;
        wb[WLO_BF16 + idx] = l;
    } else if (idx < 819200u) {
        unsigned i = idx - 786432u;
        unsigned dd = i >> 6, k = i & 63u;
        ws[WXT_OFF + i] = w_x[k * 512u + dd];
    }
}

// ---------------------------------------------------------------------------
// prep conv weights: [o][i][ky][kx] fp32 -> bf16 hi/lo [dydx][o][i]
__global__ __launch_bounds__(256) void k_prep_w(const float* __restrict__ w0,
                                                const float* __restrict__ w1,
                                                const float* __restrict__ w2,
                                                const float* __restrict__ w3,
                                                const float* __restrict__ w4,
                                                float* __restrict__ ws) {
    unsigned idx = blockIdx.x * 256u + threadIdx.x;
    if (idx >= 184320u) return;
    unsigned w = idx / 36864u, r = idx % 36864u;
    const float* src = (w == 0) ? w0 : (w == 1) ? w1 : (w == 2) ? w2 : (w == 3) ? w3 : w4;
    float f = src[r];
    __bf16 h = (__bf16)f;
    __bf16 l = (__bf16)(f - (float)h);
    unsigned o = r / 576u, rem = r % 576u, ii = rem / 9u, dydx = rem % 9u;
    __bf16* wb = (__bf16*)ws;
    unsigned dst = WPB + w * 73728u + (dydx * 64u + o) * 64u + ii;
    wb[dst] = h;
    wb[dst + 36864u] = l;
}

// ---------------------------------------------------------------------------
// xt = redu_w @ x + redu_b via bf16 hi/lo split MFMA (3 products).
__global__ __launch_bounds__(256) void k_gemm_xt_mfma(const float* __restrict__ x,
                                                      const float* __restrict__ redu_b,
                                                      float* __restrict__ ws) {
    __shared__ __bf16 xhi_s[64 * 72];
    __shared__ __bf16 xlo_s[64 * 72];
    const __bf16* __restrict__ Whi = (const __bf16*)ws;
    const __bf16* __restrict__ Wlo = ((const __bf16*)ws) + WLO_BF16;
    float* xt = ws + XT_OFF;
    const int n = blockIdx.y;
    const int d0 = blockIdx.x * 256;
    const int tid = threadIdx.x;
    const int wave = tid >> 6, lane = tid & 63;
    const int lrow = lane & 15, lkg = lane >> 4;
    const int m_base = d0 + wave * 64;
    const float* __restrict__ xn = x + n * 98304;
    const int s4 = tid & 15, cb = tid >> 4;

    v4f acc[4][4];
#pragma unroll
    for (int mt = 0; mt < 4; ++mt)
#pragma unroll
        for (int nt = 0; nt < 4; ++nt) acc[mt][nt] = (v4f){0.f, 0.f, 0.f, 0.f};

    for (int c0 = 0; c0 < 1536; c0 += 64) {
        float4 v[4];
#pragma unroll
        for (int j = 0; j < 4; ++j)
            v[j] = *(const float4*)&xn[(c0 + cb * 4 + j) * 64 + s4 * 4];
        __syncthreads();
#pragma unroll
        for (int i = 0; i < 4; ++i) {
            v4bf hv, lv;
#pragma unroll
            for (int j = 0; j < 4; ++j) {
                float f = ((const float*)&v[j])[i];
                __bf16 h = (__bf16)f;
                hv[j] = h;
                lv[j] = (__bf16)(f - (float)h);
            }
            int row = s4 * 4 + i;
            *(v4bf*)&xhi_s[row * 72 + cb * 4] = hv;
            *(v4bf*)&xlo_s[row * 72 + cb * 4] = lv;
        }
        __syncthreads();
#pragma unroll
        for (int ks = 0; ks < 64; ks += 32) {
            v8bf bh[4], bl[4], ah[4], al[4];
#pragma unroll
            for (int nt = 0; nt < 4; ++nt) {
                int off = (nt * 16 + lrow) * 72 + ks + lkg * 8;
                bh[nt] = *(const v8bf*)&xhi_s[off];
                bl[nt] = *(const v8bf*)&xlo_s[off];
            }
#pragma unroll
            for (int mt = 0; mt < 4; ++mt) {
                int gi = (m_base + mt * 16 + lrow) * 1536 + c0 + ks + lkg * 8;
                ah[mt] = *(const v8bf*)&Whi[gi];
                al[mt] = *(const v8bf*)&Wlo[gi];
            }
#pragma unroll
            for (int mt = 0; mt < 4; ++mt)
#pragma unroll
                for (int nt = 0; nt < 4; ++nt) {
                    acc[mt][nt] = __builtin_amdgcn_mfma_f32_16x16x32_bf16(
                        ah[mt], bh[nt], acc[mt][nt], 0, 0, 0);
                    acc[mt][nt] = __builtin_amdgcn_mfma_f32_16x16x32_bf16(
                        ah[mt], bl[nt], acc[mt][nt], 0, 0, 0);
                    acc[mt][nt] = __builtin_amdgcn_mfma_f32_16x16x32_bf16(
                        al[mt], bh[nt], acc[mt][nt], 0, 0, 0);
                }
        }
    }
#pragma unroll
    for (int mt = 0; mt < 4; ++mt) {
#pragma unroll
        for (int r = 0; r < 4; ++r) {
            int m = m_base + mt * 16 + lkg * 4 + r;
            float bias = redu_b[m];
#pragma unroll
            for (int nt = 0; nt < 4; ++nt) {
                int s = nt * 16 + lrow;
                xt[(n * 512 + m) * 64 + s] = acc[mt][nt][r] + bias;
            }
        }
    }
}

// ---------------------------------------------------------------------------
// wxpb = w_x @ xt ; per n: (64x512)@(512x64). grid 256, block 256, 4x4/thread.
__global__ __launch_bounds__(256) void k_gemm_wxpb(float* __restrict__ ws) {
    __shared__ float Aw[16 * 64];
    __shared__ float Bx[16 * 64];
    const float* wxT = ws + WXT_OFF;
    const float* xt = ws + XT_OFF;
    float* wxpb = ws + WXPB_OFF;
    const int n = blockIdx.x;
    const int tid = threadIdx.x;
    const int sg = tid & 15, kg = tid >> 4;

    float acc[4][4];
#pragma unroll
    for (int i = 0; i < 4; ++i)
#pragma unroll
        for (int j = 0; j < 4; ++j) acc[i][j] = 0.f;

    for (int d0 = 0; d0 < 512; d0 += 16) {
        int cc = tid >> 4, q = tid & 15;
        *(float4*)&Aw[cc * 64 + q * 4] = *(const float4*)&wxT[(d0 + cc) * 64 + q * 4];
        *(float4*)&Bx[cc * 64 + q * 4] = *(const float4*)&xt[n * 32768 + (d0 + cc) * 64 + q * 4];
        __syncthreads();
#pragma unroll
        for (int c2 = 0; c2 < 16; ++c2) {
            float4 a = *(const float4*)&Aw[c2 * 64 + kg * 4];
            float4 b = *(const float4*)&Bx[c2 * 64 + sg * 4];
            float av[4] = {a.x, a.y, a.z, a.w};
            float bv[4] = {b.x, b.y, b.z, b.w};
#pragma unroll
            for (int i = 0; i < 4; ++i)
#pragma unroll
                for (int j = 0; j < 4; ++j)
                    acc[i][j] = fmaf(av[i], bv[j], acc[i][j]);
        }
        __syncthreads();
    }
#pragma unroll
    for (int i = 0; i < 4; ++i) {
        float4 o = {acc[i][0], acc[i][1], acc[i][2], acc[i][3]};
        *(float4*)&wxpb[(n * 64 + kg * 4 + i) * 64 + sg * 4] = o;
    }
}

// ---------------------------------------------------------------------------
// generic 3x3 conv (fp32), used only for attv (256 parallel images).
__global__ __launch_bounds__(128) void k_conv3x3(const float* __restrict__ in,
                                                 const float* __restrict__ wt,
                                                 const float* __restrict__ bias,
                                                 float* __restrict__ out) {
    __shared__ float in_s[4096];
    __shared__ float w_s[16 * 576];
    const int img = blockIdx.y;
    const int k0 = blockIdx.x * 16;
    const int tid = threadIdx.x;
    const int kl = tid >> 3, y = tid & 7;
#pragma unroll
    for (int i = 0; i < 8; ++i) {
        int f = tid + i * 128;
        *(float4*)&in_s[f * 4] = *(const float4*)&in[img * 4096 + f * 4];
    }
#pragma unroll
    for (int i = 0; i < 18; ++i) {
        int f = tid + i * 128;
        *(float4*)&w_s[f * 4] = *(const float4*)&wt[k0 * 576 + f * 4];
    }
    __syncthreads();
    float o[8];
#pragma unroll
    for (int xx = 0; xx < 8; ++xx) o[xx] = 0.f;
    for (int kp = 0; kp < 64; ++kp) {
        const float* wp = &w_s[kl * 576 + kp * 9];
        float wv[9];
#pragma unroll
        for (int q = 0; q < 9; ++q) wv[q] = wp[q];
#pragma unroll
        for (int dy = 0; dy < 3; ++dy) {
            int yy = y + dy - 1;
            if (yy >= 0 && yy < 8) {
                float4 ra = *(const float4*)&in_s[kp * 64 + yy * 8];
                float4 rb = *(const float4*)&in_s[kp * 64 + yy * 8 + 4];
                float r[8] = {ra.x, ra.y, ra.z, ra.w, rb.x, rb.y, rb.z, rb.w};
                float wa = wv[dy * 3 + 0], wb = wv[dy * 3 + 1], wc = wv[dy * 3 + 2];
#pragma unroll
                for (int xx = 0; xx < 8; ++xx) {
                    float t = wb * r[xx];
                    if (xx > 0) t += wa * r[xx - 1];
                    if (xx < 7) t += wc * r[xx + 1];
                    o[xx] += t;
                }
            }
        }
    }
    float bv = bias ? bias[k0 + kl] : 0.f;
    float4 o0 = {o[0] + bv, o[1] + bv, o[2] + bv, o[3] + bv};
    float4 o1 = {o[4] + bv, o[5] + bv, o[6] + bv, o[7] + bv};
    *(float4*)&out[img * 4096 + (k0 + kl) * 64 + y * 8] = o0;
    *(float4*)&out[img * 4096 + (k0 + kl) * 64 + y * 8 + 4] = o1;
}

// ---------------------------------------------------------------------------
// 3x3 conv as 9 shifted 64x64x64 MFMA GEMMs. A = weights [dydx][o][i] bf16
// hi/lo (fp32-class), B = transposed input tS[s][72] bf16 (hi only).
// Wave covers mt (16 rows) x 2 n-tiles starting at ntb.
__device__ __forceinline__ void conv_mfma(const __bf16* __restrict__ Wh,
                                          const __bf16* __restrict__ Wl,
                                          const __bf16* tS,
                                          int l15, int kg8, int mt, int ntb,
                                          v4f acc[2]) {
    v8bf vz;
#pragma unroll
    for (int q = 0; q < 8; ++q) vz[q] = (__bf16)0.f;
    acc[0] = (v4f){0.f, 0.f, 0.f, 0.f};
    acc[1] = (v4f){0.f, 0.f, 0.f, 0.f};
    const int n0 = ntb * 16 + l15;
#pragma unroll
    for (int dy = 0; dy < 3; ++dy) {
#pragma unroll
        for (int dx = 0; dx < 3; ++dx) {
            const int y0 = (n0 >> 3) + dy - 1, x0 = (n0 & 7) + dx - 1;
            const bool okx = (unsigned)x0 < 8u;
            const bool ok0 = ((unsigned)y0 < 8u) & okx;
            const bool ok1 = ((unsigned)(y0 + 2) < 8u) & okx;
            const int s0 = ((y0 * 8 + x0) & 63) * 72 + kg8;
            const int s1 = (((y0 + 2) * 8 + x0) & 63) * 72 + kg8;
            const int wrow = ((dy * 3 + dx) * 64 + mt * 16 + l15) * 64 + kg8;
#pragma unroll
            for (int kc = 0; kc < 64; kc += 32) {
                v8bf wa = *(const v8bf*)&Wh[wrow + kc];
                v8bf wl = *(const v8bf*)&Wl[wrow + kc];
                v8bf b0 = ok0 ? *(const v8bf*)&tS[s0 + kc] : vz;
                v8bf b1 = ok1 ? *(const v8bf*)&tS[s1 + kc] : vz;
                acc[0] = __builtin_amdgcn_mfma_f32_16x16x32_bf16(wa, b0, acc[0], 0, 0, 0);
                acc[0] = __builtin_amdgcn_mfma_f32_16x16x32_bf16(wl, b0, acc[0], 0, 0, 0);
                acc[1] = __builtin_amdgcn_mfma_f32_16x16x32_bf16(wa, b1, acc[1], 0, 0, 0);
                acc[1] = __builtin_amdgcn_mfma_f32_16x16x32_bf16(wl, b1, acc[1], 0, 0, 0);
            }
        }
    }
}

__device__ __forceinline__ void write_c(float* c, const v4f acc[2],
                                        int l15, int kg, int mt, int ntb) {
#pragma unroll
    for (int i = 0; i < 2; ++i)
#pragma unroll
        for (int r = 0; r < 4; ++r)
            c[(mt * 16 + kg * 4 + r) * 65 + (ntb + i) * 16 + l15] = acc[i][r];
}

// ---------------------------------------------------------------------------
// Whole recurrence in one kernel: grid 32 (one block per b), 512 threads.
// h lives in LDS across all 8 steps; convs on MFMA.
__global__ __launch_bounds__(512) void k_recur(const float* __restrict__ att_b,
                                               const float* __restrict__ share_b,
                                               const float* __restrict__ fc1_w,
                                               const float* __restrict__ fc2_w,
                                               float* __restrict__ ws) {
    __shared__ float h_s[4096];                                   // h [k][s]
    __shared__ __attribute__((aligned(16))) __bf16 tA[64 * 72];   // T(in) [s][kp]
    __shared__ float cA[64 * 65];                                 // conv out / scratch
    __shared__ float cB[64 * 65];
    __shared__ float misc[1088];  // em|exs [0..511], ex|als [512..1023], h1|asum [1024..]
    const int b = blockIdx.x, tid = threadIdx.x;
    const int lane = tid & 63;
    const int wave = tid >> 6, mt = wave >> 1, ntb = (wave & 1) * 2;
    const int l15 = lane & 15, kg = lane >> 4, kg8 = kg * 8;
    const int kk = tid >> 3, yy = tid & 7;
    const __bf16* Wp = (const __bf16*)ws + WPB;
    const float* attv = ws + ATTV_OFF;
    const float* wxpb = ws + WXPB_OFF;
    float* hsg = ws + HS_OFF;
    float* asg = ws + ASUM_OFF;

    for (int i = tid; i < 4096; i += 512) h_s[i] = 0.f;
    const float abv = att_b[kk];
    float sb4[4];
#pragma unroll
    for (int r = 0; r < 4; ++r) sb4[r] = share_b[mt * 16 + kg * 4 + r];
    __syncthreads();

    for (int t = 0; t < 8; ++t) {
        // ---- tA = T(h)
        {
            int s = tid & 63, g = tid >> 6;
#pragma unroll
            for (int q4 = 0; q4 < 2; ++q4) {
                v4bf hv;
#pragma unroll
                for (int q = 0; q < 4; ++q) hv[q] = (__bf16)h_s[(g * 8 + q4 * 4 + q) * 64 + s];
                *(v4bf*)&tA[s * 72 + g * 8 + q4 * 4] = hv;
            }
        }
        __syncthreads();
        // ---- ah conv -> cA
        {
            v4f a[2];
            conv_mfma(Wp, Wp + 36864u, tA, l15, kg8, mt, ntb, a);
            write_c(cA, a, l15, kg, mt, ntb);
        }
        __syncthreads();
        // ---- e = relu(attv+ah); mean/max over s -> em/ex
        {
            float ah8[8];
            const float* cr = &cA[kk * 65 + yy * 8];
#pragma unroll
            for (int xx = 0; xx < 8; ++xx) ah8[xx] = cr[xx] + abv;
            for (int tp = 0; tp < 8; ++tp) {
                const float* av = &attv[((b * 8 + tp) * 64 + kk) * 64 + yy * 8];
                float4 va = *(const float4*)&av[0];
                float4 vb = *(const float4*)&av[4];
                float e[8] = {va.x, va.y, va.z, va.w, vb.x, vb.y, vb.z, vb.w};
                float s_ = 0.f, m_ = 0.f;
#pragma unroll
                for (int xx = 0; xx < 8; ++xx) {
                    float v = fmaxf(e[xx] + ah8[xx], 0.f);
                    s_ += v;
                    m_ = fmaxf(m_, v);
                }
                s_ += __shfl_down(s_, 4, 8);
                s_ += __shfl_down(s_, 2, 8);
                s_ += __shfl_down(s_, 1, 8);
                m_ = fmaxf(m_, __shfl_down(m_, 4, 8));
                m_ = fmaxf(m_, __shfl_down(m_, 2, 8));
                m_ = fmaxf(m_, __shfl_down(m_, 1, 8));
                if (yy == 0) {
                    misc[tp * 64 + kk] = s_ * (1.f / 64.f);
                    misc[512 + tp * 64 + kk] = m_;
                }
            }
        }
        __syncthreads();
        // ---- fc1 (rows 0..31 mean path, 32..63 max path)
        {
            int i2 = tid >> 3, part = tid & 7;
            int i = i2 & 31;
            const float* src = misc + ((i2 < 32) ? 0 : 512);
            const float* wrow = fc1_w + i * 512 + part * 64;
            const float* s2 = src + part * 64;
            float p = 0.f;
            for (int c = 0; c < 64; ++c) p = fmaf(wrow[c], s2[c], p);
            p += __shfl_down(p, 4, 8);
            p += __shfl_down(p, 2, 8);
            p += __shfl_down(p, 1, 8);
            if (part == 0) misc[1024 + i2] = fmaxf(p, 0.f);
        }
        __syncthreads();
        // ---- fc2 + tanh + exp -> exs at misc[0..511]
        {
            const float* w2 = fc2_w + tid * 32;
            float gm = 0.f, gx = 0.f;
#pragma unroll
            for (int i = 0; i < 32; ++i) {
                gm = fmaf(w2[i], misc[1024 + i], gm);
                gx = fmaf(w2[i], misc[1056 + i], gx);
            }
            misc[tid] = expf(tanhf(gm + gx));
        }
        __syncthreads();
        // ---- softmax over T -> als at misc[512..1023]
        {
            int k6 = tid & 63;
            float den = 0.f;
#pragma unroll
            for (int tp = 0; tp < 8; ++tp) den += misc[tp * 64 + k6];
            den += (den == 0.f) ? 1.f : 0.f;
            misc[512 + tid] = misc[tid] / den;
        }
        __syncthreads();
        // ---- wxtp (registers of (k,y) threads)
        float wx8[8];
        {
#pragma unroll
            for (int xx = 0; xx < 8; ++xx) wx8[xx] = 0.f;
            for (int tp = 0; tp < 8; ++tp) {
                float al = misc[512 + tp * 64 + kk];
                const float* src = &wxpb[((b * 8 + tp) * 64 + kk) * 64 + yy * 8];
                float4 v0 = *(const float4*)&src[0];
                float4 v1 = *(const float4*)&src[4];
                float v[8] = {v0.x, v0.y, v0.z, v0.w, v1.x, v1.y, v1.z, v1.w};
#pragma unroll
                for (int xx = 0; xx < 8; ++xx) wx8[xx] = fmaf(al, v[xx], wx8[xx]);
            }
        }
        // ---- Uz, Ur convs (input tA = T(h)), accs stay in registers
        v4f az[2], ar[2];
        conv_mfma(Wp + 2u * 73728u, Wp + 2u * 73728u + 36864u, tA, l15, kg8, mt, ntb, az);
        conv_mfma(Wp + 3u * 73728u, Wp + 3u * 73728u + 36864u, tA, l15, kg8, mt, ntb, ar);
        __syncthreads();
        // ---- tA = T(wxtp)
#pragma unroll
        for (int xx = 0; xx < 8; ++xx) tA[(yy * 8 + xx) * 72 + kk] = (__bf16)wx8[xx];
        __syncthreads();
        // ---- share conv
        v4f ash[2];
        conv_mfma(Wp + 1u * 73728u, Wp + 1u * 73728u + 36864u, tA, l15, kg8, mt, ntb, ash);
        // ---- gates (frag domain); rh -> cB
        float zf[2][4], wof[2][4];
#pragma unroll
        for (int i = 0; i < 2; ++i)
#pragma unroll
            for (int r = 0; r < 4; ++r) {
                int ko = mt * 16 + kg * 4 + r;
                int s = (ntb + i) * 16 + l15;
                float wo = ash[i][r] + sb4[r];
                float z = 1.f / (1.f + expf(-(wo + az[i][r])));
                float rr = 1.f / (1.f + expf(-(wo + ar[i][r])));
                cB[ko * 65 + s] = rr * h_s[ko * 64 + s];
                zf[i][r] = z;
                wof[i][r] = wo;
            }
        __syncthreads();
        // ---- tA = T(rh); zero asum
        {
            int s = tid & 63, g = tid >> 6;
#pragma unroll
            for (int q4 = 0; q4 < 2; ++q4) {
                v4bf hv;
#pragma unroll
                for (int q = 0; q < 4; ++q) hv[q] = (__bf16)cB[(g * 8 + q4 * 4 + q) * 65 + s];
                *(v4bf*)&tA[s * 72 + g * 8 + q4 * 4] = hv;
            }
        }
        if (tid < 64) misc[1024 + tid] = 0.f;
        __syncthreads();
        // ---- Uh conv + final update
        v4f ach[2];
        conv_mfma(Wp + 4u * 73728u, Wp + 4u * 73728u + 36864u, tA, l15, kg8, mt, ntb, ach);
#pragma unroll
        for (int r = 0; r < 4; ++r) {
            int ko = mt * 16 + kg * 4 + r;
            float rsum = 0.f;
#pragma unroll
            for (int i = 0; i < 2; ++i) {
                int s = (ntb + i) * 16 + l15;
                float hh = tanhf(wof[i][r] + ach[i][r]);
                float hold = h_s[ko * 64 + s];
                float hn = (1.f - zf[i][r]) * hh + zf[i][r] * hold;
                h_s[ko * 64 + s] = hn;
                hsg[((t * 32 + b) * 64 + ko) * 64 + s] = hn;
                rsum += hn;
            }
            rsum += __shfl_xor(rsum, 8, 16);
            rsum += __shfl_xor(rsum, 4, 16);
            rsum += __shfl_xor(rsum, 2, 16);
            rsum += __shfl_xor(rsum, 1, 16);
            if (l15 == 0) atomicAdd(&misc[1024 + ko], rsum);
        }
        __syncthreads();
        if (tid < 64) asg[b * 512 + t * 64 + tid] = misc[1024 + tid];
        __syncthreads();
    }
}

// ---------------------------------------------------------------------------
// VLAD: V[b,k,d] = sum_{t,hw} hs*xt - (sum_t asum)*centers. grid (8,32), 256 thr
__global__ __launch_bounds__(256) void k_vlad(const float* __restrict__ centers,
                                              const float* __restrict__ ws,
                                              float* __restrict__ out) {
    __shared__ float As[16 * 68];
    __shared__ float Bs[16 * 68];
    const int b = blockIdx.y;
    const int d0 = blockIdx.x * 64;
    const int tid = threadIdx.x;
    const int kq = tid & 15, dq = tid >> 4;
    const int lk = tid >> 2, q = tid & 3;
    const float* hs = ws + HS_OFF;
    const float* xt = ws + XT_OFF;
    float acc[4][4];
#pragma unroll
    for (int i = 0; i < 4; ++i)
#pragma unroll
        for (int j = 0; j < 4; ++j) acc[i][j] = 0.f;

    for (int rc = 0; rc < 512; rc += 16) {
        int t = rc >> 6, hw0 = rc & 63;
        float4 va = *(const float4*)&hs[((t * 32 + b) * 64 + lk) * 64 + hw0 + q * 4];
        float4 vb = *(const float4*)&xt[(b * 8 + t) * 32768 + (d0 + lk) * 64 + hw0 + q * 4];
        __syncthreads();
        As[(q * 4 + 0) * 68 + lk] = va.x;
        As[(q * 4 + 1) * 68 + lk] = va.y;
        As[(q * 4 + 2) * 68 + lk] = va.z;
        As[(q * 4 + 3) * 68 + lk] = va.w;
        Bs[(q * 4 + 0) * 68 + lk] = vb.x;
        Bs[(q * 4 + 1) * 68 + lk] = vb.y;
        Bs[(q * 4 + 2) * 68 + lk] = vb.z;
        Bs[(q * 4 + 3) * 68 + lk] = vb.w;
        __syncthreads();
#pragma unroll
        for (int cc = 0; cc < 16; ++cc) {
            float4 a = *(const float4*)&As[cc * 68 + kq * 4];
            float4 bb = *(const float4*)&Bs[cc * 68 + dq * 4];
            float av[4] = {a.x, a.y, a.z, a.w};
            float bv[4] = {bb.x, bb.y, bb.z, bb.w};
#pragma unroll
            for (int i = 0; i < 4; ++i)
#pragma unroll
                for (int j = 0; j < 4; ++j)
                    acc[i][j] = fmaf(av[i], bv[j], acc[i][j]);
        }
    }
    const float* asum = ws + ASUM_OFF;
#pragma unroll
    for (int i = 0; i < 4; ++i) {
        int k = kq * 4 + i;
        float at = 0.f;
#pragma unroll
        for (int tp = 0; tp < 8; ++tp) at += asum[b * 512 + tp * 64 + k];
        float4 cen = *(const float4*)&centers[k * 512 + d0 + dq * 4];
        float4 o = {acc[i][0] - at * cen.x, acc[i][1] - at * cen.y,
                    acc[i][2] - at * cen.z, acc[i][3] - at * cen.w};
        *(float4*)&out[b * 32768 + k * 512 + d0 + dq * 4] = o;
    }
}

// ---------------------------------------------------------------------------
__global__ __launch_bounds__(64) void k_norm1(float* __restrict__ out) {
    const int b = blockIdx.x >> 6, k = blockIdx.x & 63;
    float* p = out + b * 32768 + k * 512;
    const int tid = threadIdx.x;
    float v[8];
    float ss = 0.f;
#pragma unroll
    for (int i = 0; i < 8; ++i) {
        v[i] = p[tid + i * 64];
        ss = fmaf(v[i], v[i], ss);
    }
#pragma unroll
    for (int off = 32; off > 0; off >>= 1) ss += __shfl_down(ss, off, 64);
    ss = __shfl(ss, 0, 64);
    float sc = 1.f / fmaxf(sqrtf(ss), 1e-12f);
#pragma unroll
    for (int i = 0; i < 8; ++i) p[tid + i * 64] = v[i] * sc;
}

__global__ __launch_bounds__(256) void k_norm2(float* __restrict__ out) {
    __shared__ float red[4];
    __shared__ float stot;
    const int b = blockIdx.x;
    const int tid = threadIdx.x;
    float* p = out + b * 32768;
    float ss = 0.f;
    for (int i = 0; i < 32; ++i) {
        float4 v = *(const float4*)&p[tid * 4 + i * 1024];
        ss += v.x * v.x + v.y * v.y + v.z * v.z + v.w * v.w;
    }
#pragma unroll
    for (int off = 32; off > 0; off >>= 1) ss += __shfl_down(ss, off, 64);
    if ((tid & 63) == 0) red[tid >> 6] = ss;
    __syncthreads();
    if (tid == 0) stot = 1.f / fmaxf(sqrtf(red[0] + red[1] + red[2] + red[3]), 1e-12f);
    __syncthreads();
    float sc = stot;
    for (int i = 0; i < 32; ++i) {
        float4 v = *(const float4*)&p[tid * 4 + i * 1024];
        v.x *= sc; v.y *= sc; v.z *= sc; v.w *= sc;
        *(float4*)&p[tid * 4 + i * 1024] = v;
    }
}

// ---------------------------------------------------------------------------
extern "C" void kernel_launch(void* const* d_in, const int* in_sizes, int n_in,
                              void* d_out, int out_size, void* d_ws, size_t ws_size,
                              hipStream_t stream) {
    const float* x       = (const float*)d_in[0];
    const float* redu_w  = (const float*)d_in[1];
    const float* redu_b  = (const float*)d_in[2];
    const float* w_x     = (const float*)d_in[3];
    const float* att_x   = (const float*)d_in[4];
    const float* att_h_w = (const float*)d_in[5];
    const float* att_b   = (const float*)d_in[6];
    const float* share_w = (const float*)d_in[7];
    const float* share_b = (const float*)d_in[8];
    const float* U_r     = (const float*)d_in[9];
    const float* U_z     = (const float*)d_in[10];
    const float* U_h     = (const float*)d_in[11];
    const float* centers = (const float*)d_in[12];
    const float* fc1_w   = (const float*)d_in[13];
    const float* fc2_w   = (const float*)d_in[14];
    float* ws = (float*)d_ws;
    float* out = (float*)d_out;

    k_prep<<<dim3(3200), dim3(256), 0, stream>>>(redu_w, w_x, ws);
    k_prep_w<<<dim3(720), dim3(256), 0, stream>>>(att_h_w, share_w, U_z, U_r, U_h, ws);
    k_gemm_xt_mfma<<<dim3(2, 256), dim3(256), 0, stream>>>(x, redu_b, ws);
    k_gemm_wxpb<<<dim3(256), dim3(256), 0, stream>>>(ws);
    k_conv3x3<<<dim3(4, 256), dim3(128), 0, stream>>>(ws + WXPB_OFF, att_x,
                                                      (const float*)nullptr, ws + ATTV_OFF);
    k_recur<<<dim3(32), dim3(512), 0, stream>>>(att_b, share_b, fc1_w, fc2_w, ws);
    k_vlad<<<dim3(8, 32), dim3(256), 0, stream>>>(centers, ws, out);
    k_norm1<<<dim3(2048), dim3(64), 0, stream>>>(out);
    k_norm2<<<dim3(32), dim3(256), 0, stream>>>(out);
}

// Round 8
// 1150.256 us; speedup vs baseline: 1.3455x; 1.0340x over previous
//
#include <hip/hip_runtime.h>
#include <math.h>

// Problem constants
#define T_   8
#define K_   64
#define D_   512
#define CIN_ 1536
#define B_   32
#define S_   64    // H*W = 8*8
#define NT_  256   // B*T

// Workspace layout (float offsets)
#define WLO_BF16  786432u     // bf16-element offset of Wlo within bf16 view
#define WXT_OFF   786432u     // [512][64]  transposed w_x (float offset)
#define XT_OFF    819200u     // [256][512][64]
#define WXPB_OFF  9207808u    // [256][64][64]
#define ATTV_OFF  10256384u   // [256][64][64]  (n = b*8+t)
#define HS_OFF    11436032u   // [8][32][64][64]
#define ASUM_OFF  13041664u   // [32][8][64]
// conv-weight pack (bf16 elements): 5 weights x (hi 36864 + lo 36864),
// layout per weight: [dydx(9)][o(64)][i(64)].
#define WPB       25034752u

typedef __bf16 v8bf __attribute__((ext_vector_type(8)));
typedef __bf16 v4bf __attribute__((ext_vector_type(4)));
typedef float  v4f  __attribute__((ext_vector_type(4)));

// ---------------------------------------------------------------------------
// prep: split redu_w -> bf16 hi/lo, transpose w_x -> wxT[d][k]
__global__ __launch_bounds__(256) void k_prep(const float* __restrict__ redu_w,
                                              const float* __restrict__ w_x,
                                              float* __restrict__ ws) {
    unsigned idx = blockIdx.x * 256u + threadIdx.x;
    if (idx < 786432u) {
        float f = redu_w[idx];
        __bf16 h = (__bf16)f;
        __bf16 l = (__bf16)(f - (float)h);
        __bf16* wb = (__bf16*)ws;
        wb[idx] = h;
        wb[WLO_BF16 + idx] = l;
    } else if (idx < 819200u) {
        unsigned i = idx - 786432u;
        unsigned dd = i >> 6, k = i & 63u;
        ws[WXT_OFF + i] = w_x[k * 512u + dd];
    }
}

// ---------------------------------------------------------------------------
// prep conv weights: [o][i][ky][kx] fp32 -> bf16 hi/lo [dydx][o][i]
__global__ __launch_bounds__(256) void k_prep_w(const float* __restrict__ w0,
                                                const float* __restrict__ w1,
                                                const float* __restrict__ w2,
                                                const float* __restrict__ w3,
                                                const float* __restrict__ w4,
                                                float* __restrict__ ws) {
    unsigned idx = blockIdx.x * 256u + threadIdx.x;
    if (idx >= 184320u) return;
    unsigned w = idx / 36864u, r = idx % 36864u;
    const float* src = (w == 0) ? w0 : (w == 1) ? w1 : (w == 2) ? w2 : (w == 3) ? w3 : w4;
    float f = src[r];
    __bf16 h = (__bf16)f;
    __bf16 l = (__bf16)(f - (float)h);
    unsigned o = r / 576u, rem = r % 576u, ii = rem / 9u, dydx = rem % 9u;
    __bf16* wb = (__bf16*)ws;
    unsigned dst = WPB + w * 73728u + (dydx * 64u + o) * 64u + ii;
    wb[dst] = h;
    wb[dst + 36864u] = l;
}

// ---------------------------------------------------------------------------
// xt = redu_w @ x + redu_b via bf16 hi/lo split MFMA (3 products).
__global__ __launch_bounds__(256) void k_gemm_xt_mfma(const float* __restrict__ x,
                                                      const float* __restrict__ redu_b,
                                                      float* __restrict__ ws) {
    __shared__ __bf16 xhi_s[64 * 72];
    __shared__ __bf16 xlo_s[64 * 72];
    const __bf16* __restrict__ Whi = (const __bf16*)ws;
    const __bf16* __restrict__ Wlo = ((const __bf16*)ws) + WLO_BF16;
    float* xt = ws + XT_OFF;
    const int n = blockIdx.y;
    const int d0 = blockIdx.x * 256;
    const int tid = threadIdx.x;
    const int wave = tid >> 6, lane = tid & 63;
    const int lrow = lane & 15, lkg = lane >> 4;
    const int m_base = d0 + wave * 64;
    const float* __restrict__ xn = x + n * 98304;
    const int s4 = tid & 15, cb = tid >> 4;

    v4f acc[4][4];
#pragma unroll
    for (int mt = 0; mt < 4; ++mt)
#pragma unroll
        for (int nt = 0; nt < 4; ++nt) acc[mt][nt] = (v4f){0.f, 0.f, 0.f, 0.f};

    for (int c0 = 0; c0 < 1536; c0 += 64) {
        float4 v[4];
#pragma unroll
        for (int j = 0; j < 4; ++j)
            v[j] = *(const float4*)&xn[(c0 + cb * 4 + j) * 64 + s4 * 4];
        __syncthreads();
#pragma unroll
        for (int i = 0; i < 4; ++i) {
            v4bf hv, lv;
#pragma unroll
            for (int j = 0; j < 4; ++j) {
                float f = ((const float*)&v[j])[i];
                __bf16 h = (__bf16)f;
                hv[j] = h;
                lv[j] = (__bf16)(f - (float)h);
            }
            int row = s4 * 4 + i;
            *(v4bf*)&xhi_s[row * 72 + cb * 4] = hv;
            *(v4bf*)&xlo_s[row * 72 + cb * 4] = lv;
        }
        __syncthreads();
#pragma unroll
        for (int ks = 0; ks < 64; ks += 32) {
            v8bf bh[4], bl[4], ah[4], al[4];
#pragma unroll
            for (int nt = 0; nt < 4; ++nt) {
                int off = (nt * 16 + lrow) * 72 + ks + lkg * 8;
                bh[nt] = *(const v8bf*)&xhi_s[off];
                bl[nt] = *(const v8bf*)&xlo_s[off];
            }
#pragma unroll
            for (int mt = 0; mt < 4; ++mt) {
                int gi = (m_base + mt * 16 + lrow) * 1536 + c0 + ks + lkg * 8;
                ah[mt] = *(const v8bf*)&Whi[gi];
                al[mt] = *(const v8bf*)&Wlo[gi];
            }
#pragma unroll
            for (int mt = 0; mt < 4; ++mt)
#pragma unroll
                for (int nt = 0; nt < 4; ++nt) {
                    acc[mt][nt] = __builtin_amdgcn_mfma_f32_16x16x32_bf16(
                        ah[mt], bh[nt], acc[mt][nt], 0, 0, 0);
                    acc[mt][nt] = __builtin_amdgcn_mfma_f32_16x16x32_bf16(
                        ah[mt], bl[nt], acc[mt][nt], 0, 0, 0);
                    acc[mt][nt] = __builtin_amdgcn_mfma_f32_16x16x32_bf16(
                        al[mt], bh[nt], acc[mt][nt], 0, 0, 0);
                }
        }
    }
#pragma unroll
    for (int mt = 0; mt < 4; ++mt) {
#pragma unroll
        for (int r = 0; r < 4; ++r) {
            int m = m_base + mt * 16 + lkg * 4 + r;
            float bias = redu_b[m];
#pragma unroll
            for (int nt = 0; nt < 4; ++nt) {
                int s = nt * 16 + lrow;
                xt[(n * 512 + m) * 64 + s] = acc[mt][nt][r] + bias;
            }
        }
    }
}

// ---------------------------------------------------------------------------
// wxpb = w_x @ xt ; per n: (64x512)@(512x64). grid 256, block 256, 4x4/thread.
__global__ __launch_bounds__(256) void k_gemm_wxpb(float* __restrict__ ws) {
    __shared__ float Aw[16 * 64];
    __shared__ float Bx[16 * 64];
    const float* wxT = ws + WXT_OFF;
    const float* xt = ws + XT_OFF;
    float* wxpb = ws + WXPB_OFF;
    const int n = blockIdx.x;
    const int tid = threadIdx.x;
    const int sg = tid & 15, kg = tid >> 4;

    float acc[4][4];
#pragma unroll
    for (int i = 0; i < 4; ++i)
#pragma unroll
        for (int j = 0; j < 4; ++j) acc[i][j] = 0.f;

    for (int d0 = 0; d0 < 512; d0 += 16) {
        int cc = tid >> 4, q = tid & 15;
        *(float4*)&Aw[cc * 64 + q * 4] = *(const float4*)&wxT[(d0 + cc) * 64 + q * 4];
        *(float4*)&Bx[cc * 64 + q * 4] = *(const float4*)&xt[n * 32768 + (d0 + cc) * 64 + q * 4];
        __syncthreads();
#pragma unroll
        for (int c2 = 0; c2 < 16; ++c2) {
            float4 a = *(const float4*)&Aw[c2 * 64 + kg * 4];
            float4 b = *(const float4*)&Bx[c2 * 64 + sg * 4];
            float av[4] = {a.x, a.y, a.z, a.w};
            float bv[4] = {b.x, b.y, b.z, b.w};
#pragma unroll
            for (int i = 0; i < 4; ++i)
#pragma unroll
                for (int j = 0; j < 4; ++j)
                    acc[i][j] = fmaf(av[i], bv[j], acc[i][j]);
        }
        __syncthreads();
    }
#pragma unroll
    for (int i = 0; i < 4; ++i) {
        float4 o = {acc[i][0], acc[i][1], acc[i][2], acc[i][3]};
        *(float4*)&wxpb[(n * 64 + kg * 4 + i) * 64 + sg * 4] = o;
    }
}

// ---------------------------------------------------------------------------
// generic 3x3 conv (fp32), used only for attv (256 parallel images).
__global__ __launch_bounds__(128) void k_conv3x3(const float* __restrict__ in,
                                                 const float* __restrict__ wt,
                                                 const float* __restrict__ bias,
                                                 float* __restrict__ out) {
    __shared__ float in_s[4096];
    __shared__ float w_s[16 * 576];
    const int img = blockIdx.y;
    const int k0 = blockIdx.x * 16;
    const int tid = threadIdx.x;
    const int kl = tid >> 3, y = tid & 7;
#pragma unroll
    for (int i = 0; i < 8; ++i) {
        int f = tid + i * 128;
        *(float4*)&in_s[f * 4] = *(const float4*)&in[img * 4096 + f * 4];
    }
#pragma unroll
    for (int i = 0; i < 18; ++i) {
        int f = tid + i * 128;
        *(float4*)&w_s[f * 4] = *(const float4*)&wt[k0 * 576 + f * 4];
    }
    __syncthreads();
    float o[8];
#pragma unroll
    for (int xx = 0; xx < 8; ++xx) o[xx] = 0.f;
    for (int kp = 0; kp < 64; ++kp) {
        const float* wp = &w_s[kl * 576 + kp * 9];
        float wv[9];
#pragma unroll
        for (int q = 0; q < 9; ++q) wv[q] = wp[q];
#pragma unroll
        for (int dy = 0; dy < 3; ++dy) {
            int yy = y + dy - 1;
            if (yy >= 0 && yy < 8) {
                float4 ra = *(const float4*)&in_s[kp * 64 + yy * 8];
                float4 rb = *(const float4*)&in_s[kp * 64 + yy * 8 + 4];
                float r[8] = {ra.x, ra.y, ra.z, ra.w, rb.x, rb.y, rb.z, rb.w};
                float wa = wv[dy * 3 + 0], wb = wv[dy * 3 + 1], wc = wv[dy * 3 + 2];
#pragma unroll
                for (int xx = 0; xx < 8; ++xx) {
                    float t = wb * r[xx];
                    if (xx > 0) t += wa * r[xx - 1];
                    if (xx < 7) t += wc * r[xx + 1];
                    o[xx] += t;
                }
            }
        }
    }
    float bv = bias ? bias[k0 + kl] : 0.f;
    float4 o0 = {o[0] + bv, o[1] + bv, o[2] + bv, o[3] + bv};
    float4 o1 = {o[4] + bv, o[5] + bv, o[6] + bv, o[7] + bv};
    *(float4*)&out[img * 4096 + (k0 + kl) * 64 + y * 8] = o0;
    *(float4*)&out[img * 4096 + (k0 + kl) * 64 + y * 8 + 4] = o1;
}

// ---------------------------------------------------------------------------
// 3x3 conv as 9 shifted 64x64x64 MFMA GEMMs. Weight loads are batched per
// dy-row: 12 fragments (3 taps x hi/lo x 2 kc = 48 VGPRs) issued as
// independent loads ahead of that row's 24 MFMAs — 12x latency amortization
// while staying inside the 128-VGPR envelope of the known-good build.
__device__ __forceinline__ void conv_mfma(const __bf16* __restrict__ Wh,
                                          const __bf16* __restrict__ Wl,
                                          const __bf16* tS,
                                          int l15, int kg8, int mt, int ntb,
                                          v4f acc[2]) {
    v8bf vz;
#pragma unroll
    for (int q = 0; q < 8; ++q) vz[q] = (__bf16)0.f;
    v4f a0h = (v4f){0.f, 0.f, 0.f, 0.f}, a0l = (v4f){0.f, 0.f, 0.f, 0.f};
    v4f a1h = (v4f){0.f, 0.f, 0.f, 0.f}, a1l = (v4f){0.f, 0.f, 0.f, 0.f};
    const int n0 = ntb * 16 + l15;
#pragma unroll
    for (int dy = 0; dy < 3; ++dy) {
        // batch-load this dy-row's 12 weight fragments
        v8bf wh[3][2], wl[3][2];
#pragma unroll
        for (int dx = 0; dx < 3; ++dx) {
            const int wrow = ((dy * 3 + dx) * 64 + mt * 16 + l15) * 64 + kg8;
#pragma unroll
            for (int kci = 0; kci < 2; ++kci) {
                wh[dx][kci] = *(const v8bf*)&Wh[wrow + kci * 32];
                wl[dx][kci] = *(const v8bf*)&Wl[wrow + kci * 32];
            }
        }
#pragma unroll
        for (int dx = 0; dx < 3; ++dx) {
            const int y0 = (n0 >> 3) + dy - 1, x0 = (n0 & 7) + dx - 1;
            const bool okx = (unsigned)x0 < 8u;
            const bool ok0 = ((unsigned)y0 < 8u) & okx;
            const bool ok1 = ((unsigned)(y0 + 2) < 8u) & okx;
            const int s0 = ((y0 * 8 + x0) & 63) * 72 + kg8;
            const int s1 = (((y0 + 2) * 8 + x0) & 63) * 72 + kg8;
#pragma unroll
            for (int kci = 0; kci < 2; ++kci) {
                v8bf b0 = ok0 ? *(const v8bf*)&tS[s0 + kci * 32] : vz;
                v8bf b1 = ok1 ? *(const v8bf*)&tS[s1 + kci * 32] : vz;
                a0h = __builtin_amdgcn_mfma_f32_16x16x32_bf16(wh[dx][kci], b0, a0h, 0, 0, 0);
                a0l = __builtin_amdgcn_mfma_f32_16x16x32_bf16(wl[dx][kci], b0, a0l, 0, 0, 0);
                a1h = __builtin_amdgcn_mfma_f32_16x16x32_bf16(wh[dx][kci], b1, a1h, 0, 0, 0);
                a1l = __builtin_amdgcn_mfma_f32_16x16x32_bf16(wl[dx][kci], b1, a1l, 0, 0, 0);
            }
        }
    }
    acc[0] = a0h + a0l;
    acc[1] = a1h + a1l;
}

__device__ __forceinline__ void write_c(float* c, const v4f acc[2],
                                        int l15, int kg, int mt, int ntb) {
#pragma unroll
    for (int i = 0; i < 2; ++i)
#pragma unroll
        for (int r = 0; r < 4; ++r)
            c[(mt * 16 + kg * 4 + r) * 65 + (ntb + i) * 16 + l15] = acc[i][r];
}

// ---------------------------------------------------------------------------
// Whole recurrence in one kernel: grid 32 (one block per b), 512 threads.
// h lives in LDS across all 8 steps; convs on MFMA.
// NOTE: plain __launch_bounds__(512) — the (512,2) variant never survived the
// container; this attribute matches the R4 build that ran.
__global__ __launch_bounds__(512) void k_recur(const float* __restrict__ att_b,
                                               const float* __restrict__ share_b,
                                               const float* __restrict__ fc1_w,
                                               const float* __restrict__ fc2_w,
                                               float* __restrict__ ws) {
    __shared__ float h_s[4096];                                   // h [k][s]
    __shared__ __attribute__((aligned(16))) __bf16 tA[64 * 72];   // T(in) [s][kp]
    __shared__ float cA[64 * 65];                                 // conv out / scratch
    __shared__ float cB[64 * 65];
    __shared__ float misc[1088];  // em|exs [0..511], ex|als [512..1023], h1|asum [1024..]
    const int b = blockIdx.x, tid = threadIdx.x;
    const int lane = tid & 63;
    const int wave = tid >> 6, mt = wave >> 1, ntb = (wave & 1) * 2;
    const int l15 = lane & 15, kg = lane >> 4, kg8 = kg * 8;
    const int kk = tid >> 3, yy = tid & 7;
    const __bf16* Wp = (const __bf16*)ws + WPB;
    const float* attv = ws + ATTV_OFF;
    const float* wxpb = ws + WXPB_OFF;
    float* hsg = ws + HS_OFF;
    float* asg = ws + ASUM_OFF;

    for (int i = tid; i < 4096; i += 512) h_s[i] = 0.f;
    const float abv = att_b[kk];
    float sb4[4];
#pragma unroll
    for (int r = 0; r < 4; ++r) sb4[r] = share_b[mt * 16 + kg * 4 + r];
    __syncthreads();

    for (int t = 0; t < 8; ++t) {
        // ---- tA = T(h)
        {
            int s = tid & 63, g = tid >> 6;
#pragma unroll
            for (int q4 = 0; q4 < 2; ++q4) {
                v4bf hv;
#pragma unroll
                for (int q = 0; q < 4; ++q) hv[q] = (__bf16)h_s[(g * 8 + q4 * 4 + q) * 64 + s];
                *(v4bf*)&tA[s * 72 + g * 8 + q4 * 4] = hv;
            }
        }
        __syncthreads();
        // ---- ah conv -> cA
        {
            v4f a[2];
            conv_mfma(Wp, Wp + 36864u, tA, l15, kg8, mt, ntb, a);
            write_c(cA, a, l15, kg, mt, ntb);
        }
        __syncthreads();
        // ---- e = relu(attv+ah); mean/max over s -> em/ex
        {
            float ah8[8];
            const float* cr = &cA[kk * 65 + yy * 8];
#pragma unroll
            for (int xx = 0; xx < 8; ++xx) ah8[xx] = cr[xx] + abv;
            for (int tp = 0; tp < 8; ++tp) {
                const float* av = &attv[((b * 8 + tp) * 64 + kk) * 64 + yy * 8];
                float4 va = *(const float4*)&av[0];
                float4 vb = *(const float4*)&av[4];
                float e[8] = {va.x, va.y, va.z, va.w, vb.x, vb.y, vb.z, vb.w};
                float s_ = 0.f, m_ = 0.f;
#pragma unroll
                for (int xx = 0; xx < 8; ++xx) {
                    float v = fmaxf(e[xx] + ah8[xx], 0.f);
                    s_ += v;
                    m_ = fmaxf(m_, v);
                }
                s_ += __shfl_down(s_, 4, 8);
                s_ += __shfl_down(s_, 2, 8);
                s_ += __shfl_down(s_, 1, 8);
                m_ = fmaxf(m_, __shfl_down(m_, 4, 8));
                m_ = fmaxf(m_, __shfl_down(m_, 2, 8));
                m_ = fmaxf(m_, __shfl_down(m_, 1, 8));
                if (yy == 0) {
                    misc[tp * 64 + kk] = s_ * (1.f / 64.f);
                    misc[512 + tp * 64 + kk] = m_;
                }
            }
        }
        __syncthreads();
        // ---- fc1 (rows 0..31 mean path, 32..63 max path), float4 loads
        {
            int i2 = tid >> 3, part = tid & 7;
            int i = i2 & 31;
            const float* src = misc + ((i2 < 32) ? 0 : 512);
            const float* wrow = fc1_w + i * 512 + part * 64;
            const float* s2 = src + part * 64;
            float p = 0.f;
#pragma unroll
            for (int c4 = 0; c4 < 16; ++c4) {
                float4 wv = *(const float4*)&wrow[c4 * 4];
                float4 sv = *(const float4*)&s2[c4 * 4];
                p = fmaf(wv.x, sv.x, p);
                p = fmaf(wv.y, sv.y, p);
                p = fmaf(wv.z, sv.z, p);
                p = fmaf(wv.w, sv.w, p);
            }
            p += __shfl_down(p, 4, 8);
            p += __shfl_down(p, 2, 8);
            p += __shfl_down(p, 1, 8);
            if (part == 0) misc[1024 + i2] = fmaxf(p, 0.f);
        }
        __syncthreads();
        // ---- fc2 + tanh + exp -> exs at misc[0..511], float4 loads
        {
            const float* w2 = fc2_w + tid * 32;
            float gm = 0.f, gx = 0.f;
#pragma unroll
            for (int i4 = 0; i4 < 8; ++i4) {
                float4 wv = *(const float4*)&w2[i4 * 4];
                gm = fmaf(wv.x, misc[1024 + i4 * 4 + 0], gm);
                gm = fmaf(wv.y, misc[1024 + i4 * 4 + 1], gm);
                gm = fmaf(wv.z, misc[1024 + i4 * 4 + 2], gm);
                gm = fmaf(wv.w, misc[1024 + i4 * 4 + 3], gm);
                gx = fmaf(wv.x, misc[1056 + i4 * 4 + 0], gx);
                gx = fmaf(wv.y, misc[1056 + i4 * 4 + 1], gx);
                gx = fmaf(wv.z, misc[1056 + i4 * 4 + 2], gx);
                gx = fmaf(wv.w, misc[1056 + i4 * 4 + 3], gx);
            }
            misc[tid] = expf(tanhf(gm + gx));
        }
        __syncthreads();
        // ---- softmax over T -> als at misc[512..1023]
        {
            int k6 = tid & 63;
            float den = 0.f;
#pragma unroll
            for (int tp = 0; tp < 8; ++tp) den += misc[tp * 64 + k6];
            den += (den == 0.f) ? 1.f : 0.f;
            misc[512 + tid] = misc[tid] / den;
        }
        __syncthreads();
        // ---- wxtp (registers of (k,y) threads)
        float wx8[8];
        {
#pragma unroll
            for (int xx = 0; xx < 8; ++xx) wx8[xx] = 0.f;
            for (int tp = 0; tp < 8; ++tp) {
                float al = misc[512 + tp * 64 + kk];
                const float* src = &wxpb[((b * 8 + tp) * 64 + kk) * 64 + yy * 8];
                float4 v0 = *(const float4*)&src[0];
                float4 v1 = *(const float4*)&src[4];
                float v[8] = {v0.x, v0.y, v0.z, v0.w, v1.x, v1.y, v1.z, v1.w};
#pragma unroll
                for (int xx = 0; xx < 8; ++xx) wx8[xx] = fmaf(al, v[xx], wx8[xx]);
            }
        }
        // ---- Uz, Ur convs (input tA = T(h)), accs stay in registers
        v4f az[2], ar[2];
        conv_mfma(Wp + 2u * 73728u, Wp + 2u * 73728u + 36864u, tA, l15, kg8, mt, ntb, az);
        conv_mfma(Wp + 3u * 73728u, Wp + 3u * 73728u + 36864u, tA, l15, kg8, mt, ntb, ar);
        __syncthreads();
        // ---- tA = T(wxtp)
#pragma unroll
        for (int xx = 0; xx < 8; ++xx) tA[(yy * 8 + xx) * 72 + kk] = (__bf16)wx8[xx];
        __syncthreads();
        // ---- share conv
        v4f ash[2];
        conv_mfma(Wp + 1u * 73728u, Wp + 1u * 73728u + 36864u, tA, l15, kg8, mt, ntb, ash);
        // ---- gates (frag domain); rh -> cB
        float zf[2][4], wof[2][4];
#pragma unroll
        for (int i = 0; i < 2; ++i)
#pragma unroll
            for (int r = 0; r < 4; ++r) {
                int ko = mt * 16 + kg * 4 + r;
                int s = (ntb + i) * 16 + l15;
                float wo = ash[i][r] + sb4[r];
                float z = 1.f / (1.f + expf(-(wo + az[i][r])));
                float rr = 1.f / (1.f + expf(-(wo + ar[i][r])));
                cB[ko * 65 + s] = rr * h_s[ko * 64 + s];
                zf[i][r] = z;
                wof[i][r] = wo;
            }
        __syncthreads();
        // ---- tA = T(rh); zero asum
        {
            int s = tid & 63, g = tid >> 6;
#pragma unroll
            for (int q4 = 0; q4 < 2; ++q4) {
                v4bf hv;
#pragma unroll
                for (int q = 0; q < 4; ++q) hv[q] = (__bf16)cB[(g * 8 + q4 * 4 + q) * 65 + s];
                *(v4bf*)&tA[s * 72 + g * 8 + q4 * 4] = hv;
            }
        }
        if (tid < 64) misc[1024 + tid] = 0.f;
        __syncthreads();
        // ---- Uh conv + final update
        v4f ach[2];
        conv_mfma(Wp + 4u * 73728u, Wp + 4u * 73728u + 36864u, tA, l15, kg8, mt, ntb, ach);
#pragma unroll
        for (int r = 0; r < 4; ++r) {
            int ko = mt * 16 + kg * 4 + r;
            float rsum = 0.f;
#pragma unroll
            for (int i = 0; i < 2; ++i) {
                int s = (ntb + i) * 16 + l15;
                float hh = tanhf(wof[i][r] + ach[i][r]);
                float hold = h_s[ko * 64 + s];
                float hn = (1.f - zf[i][r]) * hh + zf[i][r] * hold;
                h_s[ko * 64 + s] = hn;
                hsg[((t * 32 + b) * 64 + ko) * 64 + s] = hn;
                rsum += hn;
            }
            rsum += __shfl_xor(rsum, 8, 16);
            rsum += __shfl_xor(rsum, 4, 16);
            rsum += __shfl_xor(rsum, 2, 16);
            rsum += __shfl_xor(rsum, 1, 16);
            if (l15 == 0) atomicAdd(&misc[1024 + ko], rsum);
        }
        __syncthreads();
        if (tid < 64) asg[b * 512 + t * 64 + tid] = misc[1024 + tid];
        __syncthreads();
    }
}

// ---------------------------------------------------------------------------
// VLAD: V[b,k,d] = sum_{t,hw} hs*xt - (sum_t asum)*centers. grid (8,32), 256 thr
__global__ __launch_bounds__(256) void k_vlad(const float* __restrict__ centers,
                                              const float* __restrict__ ws,
                                              float* __restrict__ out) {
    __shared__ float As[16 * 68];
    __shared__ float Bs[16 * 68];
    const int b = blockIdx.y;
    const int d0 = blockIdx.x * 64;
    const int tid = threadIdx.x;
    const int kq = tid & 15, dq = tid >> 4;
    const int lk = tid >> 2, q = tid & 3;
    const float* hs = ws + HS_OFF;
    const float* xt = ws + XT_OFF;
    float acc[4][4];
#pragma unroll
    for (int i = 0; i < 4; ++i)
#pragma unroll
        for (int j = 0; j < 4; ++j) acc[i][j] = 0.f;

    for (int rc = 0; rc < 512; rc += 16) {
        int t = rc >> 6, hw0 = rc & 63;
        float4 va = *(const float4*)&hs[((t * 32 + b) * 64 + lk) * 64 + hw0 + q * 4];
        float4 vb = *(const float4*)&xt[(b * 8 + t) * 32768 + (d0 + lk) * 64 + hw0 + q * 4];
        __syncthreads();
        As[(q * 4 + 0) * 68 + lk] = va.x;
        As[(q * 4 + 1) * 68 + lk] = va.y;
        As[(q * 4 + 2) * 68 + lk] = va.z;
        As[(q * 4 + 3) * 68 + lk] = va.w;
        Bs[(q * 4 + 0) * 68 + lk] = vb.x;
        Bs[(q * 4 + 1) * 68 + lk] = vb.y;
        Bs[(q * 4 + 2) * 68 + lk] = vb.z;
        Bs[(q * 4 + 3) * 68 + lk] = vb.w;
        __syncthreads();
#pragma unroll
        for (int cc = 0; cc < 16; ++cc) {
            float4 a = *(const float4*)&As[cc * 68 + kq * 4];
            float4 bb = *(const float4*)&Bs[cc * 68 + dq * 4];
            float av[4] = {a.x, a.y, a.z, a.w};
            float bv[4] = {bb.x, bb.y, bb.z, bb.w};
#pragma unroll
            for (int i = 0; i < 4; ++i)
#pragma unroll
                for (int j = 0; j < 4; ++j)
                    acc[i][j] = fmaf(av[i], bv[j], acc[i][j]);
        }
    }
    const float* asum = ws + ASUM_OFF;
#pragma unroll
    for (int i = 0; i < 4; ++i) {
        int k = kq * 4 + i;
        float at = 0.f;
#pragma unroll
        for (int tp = 0; tp < 8; ++tp) at += asum[b * 512 + tp * 64 + k];
        float4 cen = *(const float4*)&centers[k * 512 + d0 + dq * 4];
        float4 o = {acc[i][0] - at * cen.x, acc[i][1] - at * cen.y,
                    acc[i][2] - at * cen.z, acc[i][3] - at * cen.w};
        *(float4*)&out[b * 32768 + k * 512 + d0 + dq * 4] = o;
    }
}

// ---------------------------------------------------------------------------
__global__ __launch_bounds__(64) void k_norm1(float* __restrict__ out) {
    const int b = blockIdx.x >> 6, k = blockIdx.x & 63;
    float* p = out + b * 32768 + k * 512;
    const int tid = threadIdx.x;
    float v[8];
    float ss = 0.f;
#pragma unroll
    for (int i = 0; i < 8; ++i) {
        v[i] = p[tid + i * 64];
        ss = fmaf(v[i], v[i], ss);
    }
#pragma unroll
    for (int off = 32; off > 0; off >>= 1) ss += __shfl_down(ss, off, 64);
    ss = __shfl(ss, 0, 64);
    float sc = 1.f / fmaxf(sqrtf(ss), 1e-12f);
#pragma unroll
    for (int i = 0; i < 8; ++i) p[tid + i * 64] = v[i] * sc;
}

__global__ __launch_bounds__(256) void k_norm2(float* __restrict__ out) {
    __shared__ float red[4];
    __shared__ float stot;
    const int b = blockIdx.x;
    const int tid = threadIdx.x;
    float* p = out + b * 32768;
    float ss = 0.f;
    for (int i = 0; i < 32; ++i) {
        float4 v = *(const float4*)&p[tid * 4 + i * 1024];
        ss += v.x * v.x + v.y * v.y + v.z * v.z + v.w * v.w;
    }
#pragma unroll
    for (int off = 32; off > 0; off >>= 1) ss += __shfl_down(ss, off, 64);
    if ((tid & 63) == 0) red[tid >> 6] = ss;
    __syncthreads();
    if (tid == 0) stot = 1.f / fmaxf(sqrtf(red[0] + red[1] + red[2] + red[3]), 1e-12f);
    __syncthreads();
    float sc = stot;
    for (int i = 0; i < 32; ++i) {
        float4 v = *(const float4*)&p[tid * 4 + i * 1024];
        v.x *= sc; v.y *= sc; v.z *= sc; v.w *= sc;
        *(float4*)&p[tid * 4 + i * 1024] = v;
    }
}

// ---------------------------------------------------------------------------
extern "C" void kernel_launch(void* const* d_in, const int* in_sizes, int n_in,
                              void* d_out, int out_size, void* d_ws, size_t ws_size,
                              hipStream_t stream) {
    const float* x       = (const float*)d_in[0];
    const float* redu_w  = (const float*)d_in[1];
    const float* redu_b  = (const float*)d_in[2];
    const float* w_x     = (const float*)d_in[3];
    const float* att_x   = (const float*)d_in[4];
    const float* att_h_w = (const float*)d_in[5];
    const float* att_b   = (const float*)d_in[6];
    const float* share_w = (const float*)d_in[7];
    const float* share_b = (const float*)d_in[8];
    const float* U_r     = (const float*)d_in[9];
    const float* U_z     = (const float*)d_in[10];
    const float* U_h     = (const float*)d_in[11];
    const float* centers = (const float*)d_in[12];
    const float* fc1_w   = (const float*)d_in[13];
    const float* fc2_w   = (const float*)d_in[14];
    float* ws = (float*)d_ws;
    float* out = (float*)d_out;

    k_prep<<<dim3(3200), dim3(256), 0, stream>>>(redu_w, w_x, ws);
    k_prep_w<<<dim3(720), dim3(256), 0, stream>>>(att_h_w, share_w, U_z, U_r, U_h, ws);
    k_gemm_xt_mfma<<<dim3(2, 256), dim3(256), 0, stream>>>(x, redu_b, ws);
    k_gemm_wxpb<<<dim3(256), dim3(256), 0, stream>>>(ws);
    k_conv3x3<<<dim3(4, 256), dim3(128), 0, stream>>>(ws + WXPB_OFF, att_x,
                                                      (const float*)nullptr, ws + ATTV_OFF);
    k_recur<<<dim3(32), dim3(512), 0, stream>>>(att_b, share_b, fc1_w, fc2_w, ws);
    k_vlad<<<dim3(8, 32), dim3(256), 0, stream>>>(centers, ws, out);
    k_norm1<<<dim3(2048), dim3(64), 0, stream>>>(out);
    k_norm2<<<dim3(32), dim3(256), 0, stream>>>(out);
}